// Round 1
// baseline (377.073 us; speedup 1.0000x reference)
//
#include <hip/hip_runtime.h>

// ---------------- problem constants ----------------
#define T_ 8
#define N_ 256
#define C_ 1024
#define H_ 16
#define D_ 64
#define U_ 2056      // fused tokens per batch = T*(N+1)
#define UPAD_ 2112   // 33*64
#define MROWS_ 4112  // B*U
#define MPAD_ 4224   // 33*128
#define IMG_OUT_ELEMS 4194304  // 2*8*256*1024

typedef __attribute__((ext_vector_type(4))) float f32x4;
typedef __attribute__((ext_vector_type(8))) short s16x8;
typedef __attribute__((ext_vector_type(4))) short s16x4;

__device__ __forceinline__ short f2bf(float f) {
  union { float f; unsigned u; } a; a.f = f;
  unsigned u = a.u;
  return (short)((u + 0x7fffu + ((u >> 16) & 1u)) >> 16);
}

__device__ __forceinline__ float b2f(short s) {
  union { unsigned u; float f; } a;
  a.u = ((unsigned)(unsigned short)s) << 16;
  return a.f;
}

// bare v_exp_f32 (2^x). q is pre-scaled by log2(e) so softmax runs in exp2 domain.
__device__ __forceinline__ float exp2a(float x) {
  float r; asm("v_exp_f32 %0, %1" : "=v"(r) : "v"(x)); return r;
}

__device__ __forceinline__ unsigned cvt_pk_bf16(float lo, float hi) {
  unsigned r; asm("v_cvt_pk_bf16_f32 %0, %1, %2" : "=v"(r) : "v"(lo), "v"(hi)); return r;
}

#define ASYNC_COPY16(gp, lp)                                                   \
  __builtin_amdgcn_global_load_lds((const __attribute__((address_space(1))) void*)(gp), \
                                   (__attribute__((address_space(3))) void*)(lp), 16, 0, 0)

// ---------------- workspace offsets (bytes) ----------------
constexpr size_t OFF_XB     = 0;                         // 4224*1024*2
constexpr size_t OFF_WQKVT  = OFF_XB + 8650752;          // 3072*1024*2
constexpr size_t OFF_WPROJT = OFF_WQKVT + 6291456;       // 1024*1024*2
constexpr size_t OFF_Q      = OFF_WPROJT + 2097152;      // 32*2056*64*2
constexpr size_t OFF_K      = OFF_Q + 8421376;           // 32*2112*64*2
constexpr size_t OFF_V      = OFF_K + 8650752;           // 32*2112*64*2
constexpr size_t OFF_VT     = OFF_V + 8650752;           // 32*64*2112*2
constexpr size_t OFF_X      = OFF_VT + 8650752;          // 4224*1024*2
// total ~60 MB

// ---------------- pack img+cam -> fused-order bf16 X ----------------
__global__ __launch_bounds__(256) void pack_x_kernel(const float* __restrict__ img,
                                                     const float* __restrict__ cam,
                                                     short* __restrict__ Xb) {
  int gt = blockIdx.x * 256 + threadIdx.x;
  int e = gt << 2;                      // 4 floats per thread, exact cover of 4112*1024
  int row = e >> 10, col = e & 1023;
  int b = row / U_, u = row % U_, t = u / 257, jj = u % 257;
  const float* src = jj ? (img + ((size_t)((b * 8 + t) * 256 + (jj - 1)) << 10))
                        : (cam + ((size_t)(b * 8 + t) << 10));
  float4 f = *(const float4*)(src + col);
  s16x4 o;
  o[0] = f2bf(f.x); o[1] = f2bf(f.y); o[2] = f2bf(f.z); o[3] = f2bf(f.w);
  *(s16x4*)(Xb + ((size_t)row << 10) + col) = o;
}

// ---------------- fp32 [R][Cc] -> bf16 [Cc][R] transpose ----------------
__global__ __launch_bounds__(256) void wt_kernel(const float* __restrict__ in,
                                                 short* __restrict__ out, int R, int Cc) {
  __shared__ float tile[32][33];
  int tx = threadIdx.x & 31, ty = threadIdx.x >> 5;
  int col0 = blockIdx.x << 5, row0 = blockIdx.y << 5;
#pragma unroll
  for (int i = 0; i < 4; i++) {
    int r = ty + i * 8;
    tile[r][tx] = in[(size_t)(row0 + r) * Cc + col0 + tx];
  }
  __syncthreads();
#pragma unroll
  for (int i = 0; i < 4; i++) {
    int r = ty + i * 8;
    out[(size_t)(col0 + r) * R + row0 + tx] = f2bf(tile[tx][r]);
  }
}

// ---------------- bf16 v[bh][2112][64] -> vt[bh][64][2112] (zero pad rows) ----------------
__global__ __launch_bounds__(256) void vt_kernel(const short* __restrict__ v,
                                                 short* __restrict__ vt) {
  __shared__ __align__(16) short t2[64][65];
  int tid = threadIdx.x;
  int kt = blockIdx.x, bh = blockIdx.y;
#pragma unroll
  for (int i = 0; i < 16; i++) {
    int e = tid + i * 256; int r = e >> 6, c = e & 63;
    short vv = v[((size_t)bh * UPAD_ + kt * 64 + r) * 64 + c];
    t2[r][c] = (kt * 64 + r < U_) ? vv : (short)0;   // zero pad rows so p*V never sees garbage
  }
  __syncthreads();
#pragma unroll
  for (int i = 0; i < 16; i++) {
    int e = tid + i * 256; int d = e >> 6, c = e & 63;
    vt[((size_t)bh * 64 + d) * UPAD_ + kt * 64 + c] = t2[c][d];
  }
}

// ---------------- 128x128 bf16 GEMM, Bt is [N][K] row-major ----------------
// EPI 0: QKV epilogue (RoPE + q/k/v scatter).  EPI 1: proj epilogue (bias + out scatter).
template <int EPI>
__global__ __launch_bounds__(256) void gemm_kernel(
    const short* __restrict__ A, const short* __restrict__ Bt,
    const float* __restrict__ cosi, const float* __restrict__ sini,
    const float* __restrict__ cosc, const float* __restrict__ sinc,
    short* __restrict__ qb, short* __restrict__ kb, short* __restrict__ vb,
    const float* __restrict__ bias, float* __restrict__ outp) {
  constexpr int K = 1024;
  __shared__ __align__(16) short As[128 * 32];
  __shared__ __align__(16) short Bs[128 * 32];
  const int tid = threadIdx.x, w = tid >> 6, lane = tid & 63;
  const int l16 = lane & 15, quad = lane >> 4;
  const int bn = blockIdx.x, bm = blockIdx.y;
  const f32x4 zero = {0.f, 0.f, 0.f, 0.f};
  f32x4 acc[4][4];
#pragma unroll
  for (int i = 0; i < 4; i++)
#pragma unroll
    for (int j = 0; j < 4; j++) acc[i][j] = zero;

  const int mb = (w >> 1) << 6, nb = (w & 1) << 6;

  for (int kb0 = 0; kb0 < K; kb0 += 32) {
    __syncthreads();
#pragma unroll
    for (int i = 0; i < 2; i++) {
      int row = (w << 5) + (i << 4) + (lane >> 2);
      int cseg = (lane & 3) << 3;
      const short* ga = A + (size_t)(bm * 128 + row) * K + kb0 + cseg;
      char* la = (char*)As + ((w << 5) + (i << 4)) * 64 + lane * 16;
      ASYNC_COPY16(ga, la);
      const short* gb = Bt + (size_t)(bn * 128 + row) * K + kb0 + cseg;
      char* lb = (char*)Bs + ((w << 5) + (i << 4)) * 64 + lane * 16;
      ASYNC_COPY16(gb, lb);
    }
    __syncthreads();
    s16x8 af[4], bf[4];
#pragma unroll
    for (int mi = 0; mi < 4; mi++)
      af[mi] = *(const s16x8*)&As[(mb + mi * 16 + l16) * 32 + quad * 8];
#pragma unroll
    for (int ni = 0; ni < 4; ni++)
      bf[ni] = *(const s16x8*)&Bs[(nb + ni * 16 + l16) * 32 + quad * 8];
#pragma unroll
    for (int mi = 0; mi < 4; mi++)
#pragma unroll
      for (int ni = 0; ni < 4; ni++)
        acc[mi][ni] = __builtin_amdgcn_mfma_f32_16x16x32_bf16(af[mi], bf[ni], acc[mi][ni], 0, 0, 0);
  }

  // epilogue: C/D layout col = lane&15, row = quad*4 + reg
#pragma unroll
  for (int mi = 0; mi < 4; mi++) {
#pragma unroll
    for (int ni = 0; ni < 4; ni++) {
#pragma unroll
      for (int reg = 0; reg < 4; reg++) {
        float val = acc[mi][ni][reg];
        float partner = __shfl_xor(val, 1, 64);  // neighbor column (d^1), same row
        int R = bm * 128 + mb + mi * 16 + quad * 4 + reg;
        int Cg = bn * 128 + nb + ni * 16 + l16;
        int b = R / U_;
        if (b < 2) {
          int u = R % U_, t = u / 257, jj = u % 257;
          if constexpr (EPI == 0) {
            int which = Cg >> 10, hc = Cg & 1023, h = hc >> 6, d = hc & 63;
            int bh = b * 16 + h;
            if (which == 2) {
              vb[((size_t)bh * UPAD_ + u) * 64 + d] = f2bf(val);
            } else {
              const float *ct, *st; int pos;
              if (jj == 0) { ct = cosc; st = sinc; pos = t; }
              else         { ct = cosi; st = sini; pos = u - t - 1; }
              float cv = ct[pos * 64 + d], sv = st[pos * 64 + d];
              float o = val * cv + ((d & 1) ? partner : -partner) * sv;
              if (which == 0) {
                o *= 0.18033688f;  // fold 1/sqrt(64) * log2(e) into q (exp2-domain softmax)
                qb[((size_t)bh * U_ + u) * 64 + d] = f2bf(o);
              } else {
                kb[((size_t)bh * UPAD_ + u) * 64 + d] = f2bf(o);
              }
            }
          } else {
            float o = val + bias[Cg];
            if (jj) outp[(size_t)((b * 8 + t) * 256 + jj - 1) * 1024 + Cg] = o;
            else    outp[IMG_OUT_ELEMS + (size_t)(b * 8 + t) * 1024 + Cg] = o;
          }
        }
      }
    }
  }
}

// ---------------- fused flash attention (img queries only) ----------------
// grid: (32 q-tiles, 32 bh) = 1024 blocks = exactly 4/CU, one scheduling round.
__global__ __launch_bounds__(256) void attn_kernel(const short* __restrict__ q,
                                                   const short* __restrict__ k,
                                                   const short* __restrict__ vt,
                                                   short* __restrict__ x) {
  __shared__ __align__(16) short Kt[64 * 64];      // [kv][d] XOR-swizzled
  __shared__ __align__(16) short Vt[64 * 64];      // [d][kv] XOR-swizzled
  __shared__ __align__(16) short Pt[4 * 16 * 80];  // per-wave [q][kv], quad-XOR swizzled
  const int tid = threadIdx.x, w = tid >> 6, lane = tid & 63;
  const int l16 = lane & 15, quad = lane >> 4;
  const int qt = blockIdx.x, bh = blockIdx.y;
  const int b = bh >> 4, h = bh & 15;

  // q rows: global img row g -> fused u = g + (g>>8) + 1
  const int g = qt * 64 + w * 16 + l16;
  const int u_q = g + (g >> 8) + 1;
  const short* qp = q + ((size_t)bh * U_ + u_q) * 64;
  const s16x8 aq0 = *(const s16x8*)(qp + quad * 8);
  const s16x8 aq1 = *(const s16x8*)(qp + 32 + quad * 8);

  // async staging: lane fills LDS row sr (and sr+32), 16B granule (lane&7).
  // global source column is pre-swizzled so the LDS read side can XOR by (row&7).
  const int sr = w * 8 + (lane >> 3);
  const int sc8 = (lane & 7) ^ (lane >> 3);       // (lane&7) ^ (sr&7)
  const short* kgp = k + ((size_t)bh * UPAD_ + sr) * 64 + sc8 * 8;
  const short* vgp = vt + ((size_t)bh * 64 + sr) * UPAD_ + sc8 * 8;
  char* lk = (char*)Kt + tid * 16;
  char* lv = (char*)Vt + tid * 16;

  // swizzled LDS read columns (shorts)
  const int cK0 = (quad * 8) ^ ((l16 & 7) << 3);
  const int cK1 = (32 + quad * 8) ^ ((l16 & 7) << 3);
  const int cP0 = (quad * 8) ^ ((l16 >> 2) << 4);
  const int cP1 = (32 + quad * 8) ^ ((l16 >> 2) << 4);
  short* pw = Pt + (w * 16 + quad * 4) * 80 + l16;     // + ((ni^quad)<<4) per ni
  const short* pr = Pt + (w * 16 + l16) * 80;

  const f32x4 zero = {0.f, 0.f, 0.f, 0.f};
  float m_r[4], l_r[4];
  f32x4 o_acc[4];
#pragma unroll
  for (int r = 0; r < 4; r++) { m_r[r] = -3e38f; l_r[r] = 0.f; o_acc[r] = zero; }

  for (int kv0 = 0; kv0 < U_; kv0 += 64) {
    __syncthreads();
    ASYNC_COPY16(kgp, lk);
    ASYNC_COPY16(kgp + 2048, lk + 4096);
    ASYNC_COPY16(vgp, lv);
    ASYNC_COPY16(vgp + 32 * UPAD_, lv + 4096);
    kgp += 64 * 64;
    vgp += 64;
    __syncthreads();

    // S = Q K^T  (q pre-scaled by 1/8 * log2e)
    f32x4 s_acc[4];
#pragma unroll
    for (int ni = 0; ni < 4; ni++) {
      const s16x8 b0 = *(const s16x8*)&Kt[(ni * 16 + l16) * 64 + cK0];
      const s16x8 b1 = *(const s16x8*)&Kt[(ni * 16 + l16) * 64 + cK1];
      f32x4 z = __builtin_amdgcn_mfma_f32_16x16x32_bf16(aq0, b0, zero, 0, 0, 0);
      s_acc[ni] = __builtin_amdgcn_mfma_f32_16x16x32_bf16(aq1, b1, z, 0, 0, 0);
    }

    // mask only on the tail tile: real kv are 2048..2055 -> ni==0 && l16<8
    if (kv0 == 2048) {
#pragma unroll
      for (int ni = 0; ni < 4; ni++) {
        if (ni > 0 || l16 >= 8) {
          s_acc[ni][0] = -1e30f; s_acc[ni][1] = -1e30f;
          s_acc[ni][2] = -1e30f; s_acc[ni][3] = -1e30f;
        }
      }
    }

    // online softmax: max fully reduced per row; sum kept as per-lane partial.
#pragma unroll
    for (int reg = 0; reg < 4; reg++) {
      float mx = fmaxf(fmaxf(s_acc[0][reg], s_acc[1][reg]),
                       fmaxf(s_acc[2][reg], s_acc[3][reg]));
      mx = fmaxf(mx, __shfl_xor(mx, 1, 64));
      mx = fmaxf(mx, __shfl_xor(mx, 2, 64));
      mx = fmaxf(mx, __shfl_xor(mx, 4, 64));
      mx = fmaxf(mx, __shfl_xor(mx, 8, 64));
      if (__any(mx > m_r[reg])) {               // wave-uniform rescale-skip
        const float mnew = fmaxf(m_r[reg], mx);
        const float al = exp2a(m_r[reg] - mnew);
        m_r[reg] = mnew;
        l_r[reg] *= al;
#pragma unroll
        for (int ni = 0; ni < 4; ni++) o_acc[ni][reg] *= al;
      }
      float rs = 0.f;
#pragma unroll
      for (int ni = 0; ni < 4; ni++) {
        const float p = exp2a(s_acc[ni][reg] - m_r[reg]);
        s_acc[ni][reg] = p;
        rs += p;
      }
      l_r[reg] += rs;                            // per-lane partial; reduced at end
    }

    // P -> LDS (packed bf16 converts, swizzled, per-wave region: no barrier)
#pragma unroll
    for (int ni = 0; ni < 4; ni++) {
      const unsigned p01 = cvt_pk_bf16(s_acc[ni][0], s_acc[ni][1]);
      const unsigned p23 = cvt_pk_bf16(s_acc[ni][2], s_acc[ni][3]);
      short* pp = pw + ((ni ^ quad) << 4);
      pp[0]   = (short)(p01 & 0xffffu);
      pp[80]  = (short)(p01 >> 16);
      pp[160] = (short)(p23 & 0xffffu);
      pp[240] = (short)(p23 >> 16);
    }

    // O += P V
#pragma unroll
    for (int ks = 0; ks < 2; ks++) {
      const s16x8 ap = *(const s16x8*)&pr[ks ? cP1 : cP0];
#pragma unroll
      for (int ni = 0; ni < 4; ni++) {
        const s16x8 bv = *(const s16x8*)&Vt[(ni * 16 + l16) * 64 + (ks ? cK1 : cK0)];
        o_acc[ni] = __builtin_amdgcn_mfma_f32_16x16x32_bf16(ap, bv, o_acc[ni], 0, 0, 0);
      }
    }
  }

  // deferred l reduction across the 16 lanes of each row group
#pragma unroll
  for (int reg = 0; reg < 4; reg++) {
    float lv2 = l_r[reg];
    lv2 += __shfl_xor(lv2, 1, 64);
    lv2 += __shfl_xor(lv2, 2, 64);
    lv2 += __shfl_xor(lv2, 4, 64);
    lv2 += __shfl_xor(lv2, 8, 64);
    l_r[reg] = 1.f / lv2;
  }

  // write x[b*2056+u][h*64+d] bf16
#pragma unroll
  for (int reg = 0; reg < 4; reg++) {
    const int go = qt * 64 + w * 16 + quad * 4 + reg;
    const int u_o = go + (go >> 8) + 1;
#pragma unroll
    for (int ni = 0; ni < 4; ni++)
      x[((size_t)(b * U_ + u_o)) * 1024 + h * 64 + ni * 16 + l16] =
          f2bf(o_acc[ni][reg] * l_r[reg]);
  }
}

// ---------------- cam-query attention (8 rows/bh, frame-causal) ----------------
// grid: (8 t, 32 bh). One block per (t,bh); kv < (t+1)*257 -- mask is implicit.
__global__ __launch_bounds__(256) void cam_attn_kernel(const short* __restrict__ q,
                                                       const short* __restrict__ k,
                                                       const short* __restrict__ v,
                                                       short* __restrict__ x) {
  __shared__ float sb[U_];
  __shared__ float red[8];
  __shared__ float obuf[32][64];
  const int t = blockIdx.x, bh = blockIdx.y;
  const int b = bh >> 4, h = bh & 15;
  const int L = (t + 1) * 257;
  const int tid = threadIdx.x, lane = tid & 63, w = tid >> 6;
  const int u_q = t * 257;

  // full q row (pre-scaled, exp2 domain) in registers
  float qf[64];
  {
    const short* qpp = q + ((size_t)bh * U_ + u_q) * 64;
#pragma unroll
    for (int i = 0; i < 8; i++) {
      const s16x8 qv = *(const s16x8*)(qpp + i * 8);
#pragma unroll
      for (int j = 0; j < 8; j++) qf[i * 8 + j] = b2f(qv[j]);
    }
  }

  // scores
  float lm = -3e38f;
  for (int kv = tid; kv < L; kv += 256) {
    const short* kp = k + ((size_t)bh * UPAD_ + kv) * 64;
    float s = 0.f;
#pragma unroll
    for (int i = 0; i < 8; i++) {
      const s16x8 kvv = *(const s16x8*)(kp + i * 8);
#pragma unroll
      for (int j = 0; j < 8; j++) s += qf[i * 8 + j] * b2f(kvv[j]);
    }
    sb[kv] = s;
    lm = fmaxf(lm, s);
  }
#pragma unroll
  for (int d = 1; d < 64; d <<= 1) lm = fmaxf(lm, __shfl_xor(lm, d, 64));
  if (lane == 0) red[w] = lm;
  __syncthreads();
  const float m = fmaxf(fmaxf(red[0], red[1]), fmaxf(red[2], red[3]));

  // exp + sum
  float ls = 0.f;
  for (int kv = tid; kv < L; kv += 256) {
    const float p = exp2a(sb[kv] - m);
    sb[kv] = p;
    ls += p;
  }
#pragma unroll
  for (int d = 1; d < 64; d <<= 1) ls += __shfl_xor(ls, d, 64);
  if (lane == 0) red[4 + w] = ls;
  __syncthreads();
  const float linv = 1.f / (red[4] + red[5] + red[6] + red[7]);

  // O[d] = sum_kv p[kv] * V[kv][d]  (32 kv slots x 8-d vectors)
  const int d0 = (tid & 7) << 3;
  const int slot = tid >> 3;
  float acc[8];
#pragma unroll
  for (int j = 0; j < 8; j++) acc[j] = 0.f;
  for (int kv = slot; kv < L; kv += 32) {
    const float p = sb[kv];
    const s16x8 vv = *(const s16x8*)(v + ((size_t)bh * UPAD_ + kv) * 64 + d0);
#pragma unroll
    for (int j = 0; j < 8; j++) acc[j] += p * b2f(vv[j]);
  }
#pragma unroll
  for (int j = 0; j < 8; j++) obuf[slot][d0 + j] = acc[j];
  __syncthreads();
  if (tid < 64) {
    float s = 0.f;
#pragma unroll
    for (int i = 0; i < 32; i++) s += obuf[i][tid];
    x[((size_t)(b * U_ + u_q)) * 1024 + h * 64 + tid] = f2bf(s * linv);
  }
}

// ---------------- launch ----------------
extern "C" void kernel_launch(void* const* d_in, const int* in_sizes, int n_in,
                              void* d_out, int out_size, void* d_ws, size_t ws_size,
                              hipStream_t stream) {
  const float* img   = (const float*)d_in[0];
  const float* cam   = (const float*)d_in[1];
  const float* wqkv  = (const float*)d_in[2];
  const float* wproj = (const float*)d_in[3];
  const float* bias  = (const float*)d_in[4];
  const float* cosi  = (const float*)d_in[5];
  const float* sini  = (const float*)d_in[6];
  const float* cosc  = (const float*)d_in[7];
  const float* sinc  = (const float*)d_in[8];
  float* outp = (float*)d_out;

  char* ws = (char*)d_ws;
  short* Xb     = (short*)(ws + OFF_XB);
  short* Wqkvt  = (short*)(ws + OFF_WQKVT);
  short* Wprojt = (short*)(ws + OFF_WPROJT);
  short* qb     = (short*)(ws + OFF_Q);
  short* kb     = (short*)(ws + OFF_K);
  short* vb     = (short*)(ws + OFF_V);
  short* vtb    = (short*)(ws + OFF_VT);
  short* xb     = (short*)(ws + OFF_X);

  pack_x_kernel<<<4112, 256, 0, stream>>>(img, cam, Xb);
  wt_kernel<<<dim3(96, 32), 256, 0, stream>>>(wqkv, Wqkvt, 1024, 3072);
  wt_kernel<<<dim3(32, 32), 256, 0, stream>>>(wproj, Wprojt, 1024, 1024);
  gemm_kernel<0><<<dim3(24, 33), 256, 0, stream>>>(Xb, Wqkvt, cosi, sini, cosc, sinc,
                                                   qb, kb, vb, nullptr, nullptr);
  cam_attn_kernel<<<dim3(8, 32), 256, 0, stream>>>(qb, kb, vb, xb);
  vt_kernel<<<dim3(33, 32), 256, 0, stream>>>(vb, vtb);
  attn_kernel<<<dim3(32, 32), 256, 0, stream>>>(qb, kb, vtb, xb);
  gemm_kernel<1><<<dim3(8, 33), 256, 0, stream>>>(xb, Wprojt, nullptr, nullptr, nullptr, nullptr,
                                                  nullptr, nullptr, nullptr, bias, outp);
}

// Round 2
// 364.050 us; speedup vs baseline: 1.0358x; 1.0358x over previous
//
#include <hip/hip_runtime.h>

// ---------------- problem constants ----------------
#define T_ 8
#define N_ 256
#define C_ 1024
#define H_ 16
#define D_ 64
#define U_ 2056      // fused tokens per batch = T*(N+1)
#define UPAD_ 2112   // 33*64
#define MROWS_ 4112  // B*U
#define MPAD_ 4224   // 33*128
#define IMG_OUT_ELEMS 4194304  // 2*8*256*1024

typedef __attribute__((ext_vector_type(4))) float f32x4;
typedef __attribute__((ext_vector_type(8))) short s16x8;
typedef __attribute__((ext_vector_type(4))) short s16x4;

__device__ __forceinline__ short f2bf(float f) {
  union { float f; unsigned u; } a; a.f = f;
  unsigned u = a.u;
  return (short)((u + 0x7fffu + ((u >> 16) & 1u)) >> 16);
}

__device__ __forceinline__ float b2f(short s) {
  union { unsigned u; float f; } a;
  a.u = ((unsigned)(unsigned short)s) << 16;
  return a.f;
}

// bare v_exp_f32 (2^x). q is pre-scaled by log2(e) so softmax runs in exp2 domain.
__device__ __forceinline__ float exp2a(float x) {
  float r; asm("v_exp_f32 %0, %1" : "=v"(r) : "v"(x)); return r;
}

__device__ __forceinline__ unsigned cvt_pk_bf16(float lo, float hi) {
  unsigned r; asm("v_cvt_pk_bf16_f32 %0, %1, %2" : "=v"(r) : "v"(lo), "v"(hi)); return r;
}

#define ASYNC_COPY16(gp, lp)                                                   \
  __builtin_amdgcn_global_load_lds((const __attribute__((address_space(1))) void*)(gp), \
                                   (__attribute__((address_space(3))) void*)(lp), 16, 0, 0)

// ---------------- workspace offsets (bytes) ----------------
constexpr size_t OFF_XB     = 0;                         // 4224*1024*2
constexpr size_t OFF_WQKVT  = OFF_XB + 8650752;          // 3072*1024*2
constexpr size_t OFF_WPROJT = OFF_WQKVT + 6291456;       // 1024*1024*2
constexpr size_t OFF_Q      = OFF_WPROJT + 2097152;      // 32*2056*64*2
constexpr size_t OFF_K      = OFF_Q + 8421376;           // 32*2112*64*2
constexpr size_t OFF_V      = OFF_K + 8650752;           // 32*2112*64*2
constexpr size_t OFF_VT     = OFF_V + 8650752;           // 32*64*2112*2
constexpr size_t OFF_X      = OFF_VT + 8650752;          // 4224*1024*2
// total ~60 MB

// ---------------- pack img+cam -> fused-order bf16 X ----------------
__global__ __launch_bounds__(256) void pack_x_kernel(const float* __restrict__ img,
                                                     const float* __restrict__ cam,
                                                     short* __restrict__ Xb) {
  int gt = blockIdx.x * 256 + threadIdx.x;
  int e = gt << 2;                      // 4 floats per thread, exact cover of 4112*1024
  int row = e >> 10, col = e & 1023;
  int b = row / U_, u = row % U_, t = u / 257, jj = u % 257;
  const float* src = jj ? (img + ((size_t)((b * 8 + t) * 256 + (jj - 1)) << 10))
                        : (cam + ((size_t)(b * 8 + t) << 10));
  float4 f = *(const float4*)(src + col);
  s16x4 o;
  o[0] = f2bf(f.x); o[1] = f2bf(f.y); o[2] = f2bf(f.z); o[3] = f2bf(f.w);
  *(s16x4*)(Xb + ((size_t)row << 10) + col) = o;
}

// ---------------- fp32 [R][Cc] -> bf16 [Cc][R] transpose ----------------
__global__ __launch_bounds__(256) void wt_kernel(const float* __restrict__ in,
                                                 short* __restrict__ out, int R, int Cc) {
  __shared__ float tile[32][33];
  int tx = threadIdx.x & 31, ty = threadIdx.x >> 5;
  int col0 = blockIdx.x << 5, row0 = blockIdx.y << 5;
#pragma unroll
  for (int i = 0; i < 4; i++) {
    int r = ty + i * 8;
    tile[r][tx] = in[(size_t)(row0 + r) * Cc + col0 + tx];
  }
  __syncthreads();
#pragma unroll
  for (int i = 0; i < 4; i++) {
    int r = ty + i * 8;
    out[(size_t)(col0 + r) * R + row0 + tx] = f2bf(tile[tx][r]);
  }
}

// ---------------- bf16 v[bh][2112][64] -> vt[bh][64][2112] (zero pad rows) ----------------
__global__ __launch_bounds__(256) void vt_kernel(const short* __restrict__ v,
                                                 short* __restrict__ vt) {
  __shared__ __align__(16) short t2[64][65];
  int tid = threadIdx.x;
  int kt = blockIdx.x, bh = blockIdx.y;
#pragma unroll
  for (int i = 0; i < 16; i++) {
    int e = tid + i * 256; int r = e >> 6, c = e & 63;
    short vv = v[((size_t)bh * UPAD_ + kt * 64 + r) * 64 + c];
    t2[r][c] = (kt * 64 + r < U_) ? vv : (short)0;   // zero pad rows so p*V never sees garbage
  }
  __syncthreads();
#pragma unroll
  for (int i = 0; i < 16; i++) {
    int e = tid + i * 256; int d = e >> 6, c = e & 63;
    vt[((size_t)bh * 64 + d) * UPAD_ + kt * 64 + c] = t2[c][d];
  }
}

// ---------------- 128x128 bf16 GEMM, Bt is [N][K] row-major ----------------
// EPI 0: QKV epilogue (RoPE + q/k/v scatter).  EPI 1: proj epilogue (bias + out scatter).
template <int EPI>
__global__ __launch_bounds__(256) void gemm_kernel(
    const short* __restrict__ A, const short* __restrict__ Bt,
    const float* __restrict__ cosi, const float* __restrict__ sini,
    const float* __restrict__ cosc, const float* __restrict__ sinc,
    short* __restrict__ qb, short* __restrict__ kb, short* __restrict__ vb,
    const float* __restrict__ bias, float* __restrict__ outp) {
  constexpr int K = 1024;
  __shared__ __align__(16) short As[128 * 32];
  __shared__ __align__(16) short Bs[128 * 32];
  const int tid = threadIdx.x, w = tid >> 6, lane = tid & 63;
  const int l16 = lane & 15, quad = lane >> 4;
  const int bn = blockIdx.x, bm = blockIdx.y;
  const f32x4 zero = {0.f, 0.f, 0.f, 0.f};
  f32x4 acc[4][4];
#pragma unroll
  for (int i = 0; i < 4; i++)
#pragma unroll
    for (int j = 0; j < 4; j++) acc[i][j] = zero;

  const int mb = (w >> 1) << 6, nb = (w & 1) << 6;

  for (int kb0 = 0; kb0 < K; kb0 += 32) {
    __syncthreads();
#pragma unroll
    for (int i = 0; i < 2; i++) {
      int row = (w << 5) + (i << 4) + (lane >> 2);
      int cseg = (lane & 3) << 3;
      const short* ga = A + (size_t)(bm * 128 + row) * K + kb0 + cseg;
      char* la = (char*)As + ((w << 5) + (i << 4)) * 64 + lane * 16;
      ASYNC_COPY16(ga, la);
      const short* gb = Bt + (size_t)(bn * 128 + row) * K + kb0 + cseg;
      char* lb = (char*)Bs + ((w << 5) + (i << 4)) * 64 + lane * 16;
      ASYNC_COPY16(gb, lb);
    }
    __syncthreads();
    s16x8 af[4], bf[4];
#pragma unroll
    for (int mi = 0; mi < 4; mi++)
      af[mi] = *(const s16x8*)&As[(mb + mi * 16 + l16) * 32 + quad * 8];
#pragma unroll
    for (int ni = 0; ni < 4; ni++)
      bf[ni] = *(const s16x8*)&Bs[(nb + ni * 16 + l16) * 32 + quad * 8];
#pragma unroll
    for (int mi = 0; mi < 4; mi++)
#pragma unroll
      for (int ni = 0; ni < 4; ni++)
        acc[mi][ni] = __builtin_amdgcn_mfma_f32_16x16x32_bf16(af[mi], bf[ni], acc[mi][ni], 0, 0, 0);
  }

  // epilogue: C/D layout col = lane&15, row = quad*4 + reg
#pragma unroll
  for (int mi = 0; mi < 4; mi++) {
#pragma unroll
    for (int ni = 0; ni < 4; ni++) {
#pragma unroll
      for (int reg = 0; reg < 4; reg++) {
        float val = acc[mi][ni][reg];
        float partner = __shfl_xor(val, 1, 64);  // neighbor column (d^1), same row
        int R = bm * 128 + mb + mi * 16 + quad * 4 + reg;
        int Cg = bn * 128 + nb + ni * 16 + l16;
        int b = R / U_;
        if (b < 2) {
          int u = R % U_, t = u / 257, jj = u % 257;
          if constexpr (EPI == 0) {
            int which = Cg >> 10, hc = Cg & 1023, h = hc >> 6, d = hc & 63;
            int bh = b * 16 + h;
            if (which == 2) {
              vb[((size_t)bh * UPAD_ + u) * 64 + d] = f2bf(val);
            } else {
              const float *ct, *st; int pos;
              if (jj == 0) { ct = cosc; st = sinc; pos = t; }
              else         { ct = cosi; st = sini; pos = u - t - 1; }
              float cv = ct[pos * 64 + d], sv = st[pos * 64 + d];
              float o = val * cv + ((d & 1) ? partner : -partner) * sv;
              if (which == 0) {
                o *= 0.18033688f;  // fold 1/sqrt(64) * log2(e) into q (exp2-domain softmax)
                qb[((size_t)bh * U_ + u) * 64 + d] = f2bf(o);
              } else {
                kb[((size_t)bh * UPAD_ + u) * 64 + d] = f2bf(o);
              }
            }
          } else {
            float o = val + bias[Cg];
            if (jj) outp[(size_t)((b * 8 + t) * 256 + jj - 1) * 1024 + Cg] = o;
            else    outp[IMG_OUT_ELEMS + (size_t)(b * 8 + t) * 1024 + Cg] = o;
          }
        }
      }
    }
  }
}

// ---------------- fused flash attention (img queries only) ----------------
// grid: 1024 1-D blocks; decode so each XCD owns 4 bh (K/V L2-resident, T1 swizzle).
// Pipeline: reg-staged K/V (T14) -- loads for tile t+1 issue right after the
// "LDS ready" barrier of tile t and land via ds_write at the top of t+1.
__global__ __launch_bounds__(256) void attn_kernel(const short* __restrict__ q,
                                                   const short* __restrict__ k,
                                                   const short* __restrict__ vt,
                                                   short* __restrict__ x) {
  __shared__ __align__(16) short Kt[64 * 64];      // [kv][d] XOR-swizzled
  __shared__ __align__(16) short Vt[64 * 64];      // [d][kv] XOR-swizzled
  __shared__ __align__(16) short Pt[4 * 16 * 80];  // per-wave [q][kv], quad-XOR swizzled
  const int tid = threadIdx.x, w = tid >> 6, lane = tid & 63;
  const int l16 = lane & 15, quad = lane >> 4;
  // XCD-aware decode: dispatch round-robins blockIdx across 8 XCDs; give XCD
  // (flat&7) the bh group 4*(flat&7)..+3 so K+V (2.2 MB) stay in its L2.
  const int flat = blockIdx.x;
  const int slot = flat >> 3;
  const int bh = ((flat & 7) << 2) + (slot >> 5);
  const int qt = slot & 31;
  const int b = bh >> 4, h = bh & 15;

  // q rows: global img row g -> fused u = g + (g>>8) + 1
  const int g = qt * 64 + w * 16 + l16;
  const int u_q = g + (g >> 8) + 1;
  const short* qp = q + ((size_t)bh * U_ + u_q) * 64;
  const s16x8 aq0 = *(const s16x8*)(qp + quad * 8);
  const s16x8 aq1 = *(const s16x8*)(qp + 32 + quad * 8);

  // reg-staging geometry: lane stages rows sr and sr+32, 16B granule c8.
  // Global reads are linear; swizzle is applied on the ds_write side.
  const int sr = w * 8 + (lane >> 3);              // 0..31
  const int c8 = lane & 7;
  const short* kg = k + ((size_t)bh * UPAD_ + sr) * 64 + (c8 << 3);
  const short* vg = vt + ((size_t)bh * 64 + sr) * UPAD_ + (c8 << 3);
  const int swz = ((c8 ^ (sr & 7)) << 3);          // (sr+32)&7 == sr&7
  short* const wk0 = &Kt[sr * 64 + swz];
  short* const wk1 = &Kt[(sr + 32) * 64 + swz];
  short* const wv0 = &Vt[sr * 64 + swz];
  short* const wv1 = &Vt[(sr + 32) * 64 + swz];

  // swizzled LDS read columns (shorts)
  const int cK0 = (quad * 8) ^ ((l16 & 7) << 3);
  const int cK1 = (32 + quad * 8) ^ ((l16 & 7) << 3);
  const int cP0 = (quad * 8) ^ ((l16 >> 2) << 4);
  const int cP1 = (32 + quad * 8) ^ ((l16 >> 2) << 4);
  short* pw = Pt + (w * 16 + quad * 4) * 80 + l16;     // + ((ni^quad)<<4) per ni
  const short* pr = Pt + (w * 16 + l16) * 80;

  const f32x4 zero = {0.f, 0.f, 0.f, 0.f};
  float m_r[4], l_r[4];
  f32x4 o_acc[4];
#pragma unroll
  for (int r = 0; r < 4; r++) { m_r[r] = -3e38f; l_r[r] = 0.f; o_acc[r] = zero; }

  // prologue: stage tile 0 into regs
  s16x8 rk0 = *(const s16x8*)(kg);
  s16x8 rk1 = *(const s16x8*)(kg + 2048);
  s16x8 rv0 = *(const s16x8*)(vg);
  s16x8 rv1 = *(const s16x8*)(vg + 32 * UPAD_);
  kg += 64 * 64;
  vg += 64;

  for (int kv0 = 0; kv0 < U_; kv0 += 64) {
    __syncthreads();                 // prev tile's LDS reads complete
    *(s16x8*)wk0 = rk0;
    *(s16x8*)wk1 = rk1;
    *(s16x8*)wv0 = rv0;
    *(s16x8*)wv1 = rv1;
    __syncthreads();                 // LDS ready
    if (kv0 + 64 < U_) {             // issue next-tile loads; hide under compute
      rk0 = *(const s16x8*)(kg);
      rk1 = *(const s16x8*)(kg + 2048);
      rv0 = *(const s16x8*)(vg);
      rv1 = *(const s16x8*)(vg + 32 * UPAD_);
      kg += 64 * 64;
      vg += 64;
    }

    // S = Q K^T  (q pre-scaled by 1/8 * log2e)
    f32x4 s_acc[4];
#pragma unroll
    for (int ni = 0; ni < 4; ni++) {
      const s16x8 b0 = *(const s16x8*)&Kt[(ni * 16 + l16) * 64 + cK0];
      const s16x8 b1 = *(const s16x8*)&Kt[(ni * 16 + l16) * 64 + cK1];
      f32x4 z = __builtin_amdgcn_mfma_f32_16x16x32_bf16(aq0, b0, zero, 0, 0, 0);
      s_acc[ni] = __builtin_amdgcn_mfma_f32_16x16x32_bf16(aq1, b1, z, 0, 0, 0);
    }

    // mask only on the tail tile: real kv are 2048..2055 -> ni==0 && l16<8
    if (kv0 == 2048) {
#pragma unroll
      for (int ni = 0; ni < 4; ni++) {
        if (ni > 0 || l16 >= 8) {
          s_acc[ni][0] = -1e30f; s_acc[ni][1] = -1e30f;
          s_acc[ni][2] = -1e30f; s_acc[ni][3] = -1e30f;
        }
      }
    }

    // online softmax: max fully reduced per row; sum kept as per-lane partial.
    // T13 defer-max: skip the rescale while the max grows by < 8 (exp2 domain).
#pragma unroll
    for (int reg = 0; reg < 4; reg++) {
      float mx = fmaxf(fmaxf(s_acc[0][reg], s_acc[1][reg]),
                       fmaxf(s_acc[2][reg], s_acc[3][reg]));
      mx = fmaxf(mx, __shfl_xor(mx, 1, 64));
      mx = fmaxf(mx, __shfl_xor(mx, 2, 64));
      mx = fmaxf(mx, __shfl_xor(mx, 4, 64));
      mx = fmaxf(mx, __shfl_xor(mx, 8, 64));
      if (__any(mx > m_r[reg] + 8.f)) {          // wave-uniform rescale-skip
        const float mnew = fmaxf(m_r[reg], mx);
        const float al = exp2a(m_r[reg] - mnew);
        m_r[reg] = mnew;
        l_r[reg] *= al;
#pragma unroll
        for (int ni = 0; ni < 4; ni++) o_acc[ni][reg] *= al;
      }
      float rs = 0.f;
#pragma unroll
      for (int ni = 0; ni < 4; ni++) {
        const float p = exp2a(s_acc[ni][reg] - m_r[reg]);
        s_acc[ni][reg] = p;
        rs += p;
      }
      l_r[reg] += rs;                            // per-lane partial; reduced at end
    }

    // P -> LDS (packed bf16 converts, swizzled, per-wave region: no barrier)
#pragma unroll
    for (int ni = 0; ni < 4; ni++) {
      const unsigned p01 = cvt_pk_bf16(s_acc[ni][0], s_acc[ni][1]);
      const unsigned p23 = cvt_pk_bf16(s_acc[ni][2], s_acc[ni][3]);
      short* pp = pw + ((ni ^ quad) << 4);
      pp[0]   = (short)(p01 & 0xffffu);
      pp[80]  = (short)(p01 >> 16);
      pp[160] = (short)(p23 & 0xffffu);
      pp[240] = (short)(p23 >> 16);
    }

    // O += P V
#pragma unroll
    for (int ks = 0; ks < 2; ks++) {
      const s16x8 ap = *(const s16x8*)&pr[ks ? cP1 : cP0];
#pragma unroll
      for (int ni = 0; ni < 4; ni++) {
        const s16x8 bv = *(const s16x8*)&Vt[(ni * 16 + l16) * 64 + (ks ? cK1 : cK0)];
        o_acc[ni] = __builtin_amdgcn_mfma_f32_16x16x32_bf16(ap, bv, o_acc[ni], 0, 0, 0);
      }
    }
  }

  // deferred l reduction across the 16 lanes of each row group
#pragma unroll
  for (int reg = 0; reg < 4; reg++) {
    float lv2 = l_r[reg];
    lv2 += __shfl_xor(lv2, 1, 64);
    lv2 += __shfl_xor(lv2, 2, 64);
    lv2 += __shfl_xor(lv2, 4, 64);
    lv2 += __shfl_xor(lv2, 8, 64);
    l_r[reg] = 1.f / lv2;
  }

  // write x[b*2056+u][h*64+d] bf16
#pragma unroll
  for (int reg = 0; reg < 4; reg++) {
    const int go = qt * 64 + w * 16 + quad * 4 + reg;
    const int u_o = go + (go >> 8) + 1;
#pragma unroll
    for (int ni = 0; ni < 4; ni++)
      x[((size_t)(b * U_ + u_o)) * 1024 + h * 64 + ni * 16 + l16] =
          f2bf(o_acc[ni][reg] * l_r[reg]);
  }
}

// ---------------- cam-query attention (8 rows/bh, frame-causal) ----------------
// grid: (8 t, 32 bh). One block per (t,bh); kv < (t+1)*257 -- mask is implicit.
__global__ __launch_bounds__(256) void cam_attn_kernel(const short* __restrict__ q,
                                                       const short* __restrict__ k,
                                                       const short* __restrict__ v,
                                                       short* __restrict__ x) {
  __shared__ float sb[U_];
  __shared__ float red[8];
  __shared__ float obuf[32][64];
  const int t = blockIdx.x, bh = blockIdx.y;
  const int b = bh >> 4, h = bh & 15;
  const int L = (t + 1) * 257;
  const int tid = threadIdx.x, lane = tid & 63, w = tid >> 6;
  const int u_q = t * 257;

  // full q row (pre-scaled, exp2 domain) in registers
  float qf[64];
  {
    const short* qpp = q + ((size_t)bh * U_ + u_q) * 64;
#pragma unroll
    for (int i = 0; i < 8; i++) {
      const s16x8 qv = *(const s16x8*)(qpp + i * 8);
#pragma unroll
      for (int j = 0; j < 8; j++) qf[i * 8 + j] = b2f(qv[j]);
    }
  }

  // scores
  float lm = -3e38f;
  for (int kv = tid; kv < L; kv += 256) {
    const short* kp = k + ((size_t)bh * UPAD_ + kv) * 64;
    float s = 0.f;
#pragma unroll
    for (int i = 0; i < 8; i++) {
      const s16x8 kvv = *(const s16x8*)(kp + i * 8);
#pragma unroll
      for (int j = 0; j < 8; j++) s += qf[i * 8 + j] * b2f(kvv[j]);
    }
    sb[kv] = s;
    lm = fmaxf(lm, s);
  }
#pragma unroll
  for (int d = 1; d < 64; d <<= 1) lm = fmaxf(lm, __shfl_xor(lm, d, 64));
  if (lane == 0) red[w] = lm;
  __syncthreads();
  const float m = fmaxf(fmaxf(red[0], red[1]), fmaxf(red[2], red[3]));

  // exp + sum
  float ls = 0.f;
  for (int kv = tid; kv < L; kv += 256) {
    const float p = exp2a(sb[kv] - m);
    sb[kv] = p;
    ls += p;
  }
#pragma unroll
  for (int d = 1; d < 64; d <<= 1) ls += __shfl_xor(ls, d, 64);
  if (lane == 0) red[4 + w] = ls;
  __syncthreads();
  const float linv = 1.f / (red[4] + red[5] + red[6] + red[7]);

  // O[d] = sum_kv p[kv] * V[kv][d]  (32 kv slots x 8-d vectors)
  const int d0 = (tid & 7) << 3;
  const int slot = tid >> 3;
  float acc[8];
#pragma unroll
  for (int j = 0; j < 8; j++) acc[j] = 0.f;
  for (int kv = slot; kv < L; kv += 32) {
    const float p = sb[kv];
    const s16x8 vv = *(const s16x8*)(v + ((size_t)bh * UPAD_ + kv) * 64 + d0);
#pragma unroll
    for (int j = 0; j < 8; j++) acc[j] += p * b2f(vv[j]);
  }
#pragma unroll
  for (int j = 0; j < 8; j++) obuf[slot][d0 + j] = acc[j];
  __syncthreads();
  if (tid < 64) {
    float s = 0.f;
#pragma unroll
    for (int i = 0; i < 32; i++) s += obuf[i][tid];
    x[((size_t)(b * U_ + u_q)) * 1024 + h * 64 + tid] = f2bf(s * linv);
  }
}

// ---------------- launch ----------------
extern "C" void kernel_launch(void* const* d_in, const int* in_sizes, int n_in,
                              void* d_out, int out_size, void* d_ws, size_t ws_size,
                              hipStream_t stream) {
  const float* img   = (const float*)d_in[0];
  const float* cam   = (const float*)d_in[1];
  const float* wqkv  = (const float*)d_in[2];
  const float* wproj = (const float*)d_in[3];
  const float* bias  = (const float*)d_in[4];
  const float* cosi  = (const float*)d_in[5];
  const float* sini  = (const float*)d_in[6];
  const float* cosc  = (const float*)d_in[7];
  const float* sinc  = (const float*)d_in[8];
  float* outp = (float*)d_out;

  char* ws = (char*)d_ws;
  short* Xb     = (short*)(ws + OFF_XB);
  short* Wqkvt  = (short*)(ws + OFF_WQKVT);
  short* Wprojt = (short*)(ws + OFF_WPROJT);
  short* qb     = (short*)(ws + OFF_Q);
  short* kb     = (short*)(ws + OFF_K);
  short* vb     = (short*)(ws + OFF_V);
  short* vtb    = (short*)(ws + OFF_VT);
  short* xb     = (short*)(ws + OFF_X);

  pack_x_kernel<<<4112, 256, 0, stream>>>(img, cam, Xb);
  wt_kernel<<<dim3(96, 32), 256, 0, stream>>>(wqkv, Wqkvt, 1024, 3072);
  wt_kernel<<<dim3(32, 32), 256, 0, stream>>>(wproj, Wprojt, 1024, 1024);
  gemm_kernel<0><<<dim3(24, 33), 256, 0, stream>>>(Xb, Wqkvt, cosi, sini, cosc, sinc,
                                                   qb, kb, vb, nullptr, nullptr);
  cam_attn_kernel<<<dim3(8, 32), 256, 0, stream>>>(qb, kb, vb, xb);
  vt_kernel<<<dim3(33, 32), 256, 0, stream>>>(vb, vtb);
  attn_kernel<<<1024, 256, 0, stream>>>(qb, kb, vtb, xb);
  gemm_kernel<1><<<dim3(8, 33), 256, 0, stream>>>(xb, Wprojt, nullptr, nullptr, nullptr, nullptr,
                                                  nullptr, nullptr, nullptr, bias, outp);
}

// Round 3
// 312.520 us; speedup vs baseline: 1.2066x; 1.1649x over previous
//
#include <hip/hip_runtime.h>

// ---------------- problem constants ----------------
#define T_ 8
#define N_ 256
#define C_ 1024
#define H_ 16
#define D_ 64
#define U_ 2056      // fused tokens per batch = T*(N+1)
#define UPAD_ 2112   // 33*64
#define MROWS_ 4112  // B*U
#define MPAD_ 4224   // 33*128
#define IMG_OUT_ELEMS 4194304  // 2*8*256*1024

typedef __attribute__((ext_vector_type(4))) float f32x4;
typedef __attribute__((ext_vector_type(8))) short s16x8;
typedef __attribute__((ext_vector_type(4))) short s16x4;

__device__ __forceinline__ short f2bf(float f) {
  union { float f; unsigned u; } a; a.f = f;
  unsigned u = a.u;
  return (short)((u + 0x7fffu + ((u >> 16) & 1u)) >> 16);
}

__device__ __forceinline__ float b2f(short s) {
  union { unsigned u; float f; } a;
  a.u = ((unsigned)(unsigned short)s) << 16;
  return a.f;
}

// bare v_exp_f32 (2^x). q is pre-scaled by log2(e) so softmax runs in exp2 domain.
__device__ __forceinline__ float exp2a(float x) {
  float r; asm("v_exp_f32 %0, %1" : "=v"(r) : "v"(x)); return r;
}

__device__ __forceinline__ unsigned cvt_pk_bf16(float lo, float hi) {
  unsigned r; asm("v_cvt_pk_bf16_f32 %0, %1, %2" : "=v"(r) : "v"(lo), "v"(hi)); return r;
}

#define ASYNC_COPY16(gp, lp)                                                   \
  __builtin_amdgcn_global_load_lds((const __attribute__((address_space(1))) void*)(gp), \
                                   (__attribute__((address_space(3))) void*)(lp), 16, 0, 0)

// ---------------- workspace offsets (bytes) ----------------
constexpr size_t OFF_XB     = 0;                         // 4224*1024*2
constexpr size_t OFF_WQKVT  = OFF_XB + 8650752;          // 3072*1024*2
constexpr size_t OFF_WPROJT = OFF_WQKVT + 6291456;       // 1024*1024*2
constexpr size_t OFF_Q      = OFF_WPROJT + 2097152;      // 32*2056*64*2
constexpr size_t OFF_K      = OFF_Q + 8421376;           // 32*2112*64*2
constexpr size_t OFF_V      = OFF_K + 8650752;           // 32*2112*64*2
constexpr size_t OFF_VT     = OFF_V + 8650752;           // 32*64*2112*2
constexpr size_t OFF_X      = OFF_VT + 8650752;          // 4224*1024*2
// total ~60 MB

// ---------------- fused prep: pack X + both weight transposes ----------------
// blocks 0..4111: pack img+cam -> fused-order bf16 X
// blocks 4112..7183: wqkv [1024][3072] f32 -> Wqkvt [3072][1024] bf16
// blocks 7184..8207: wproj [1024][1024] f32 -> Wprojt [1024][1024] bf16
__global__ __launch_bounds__(256) void prep_kernel(const float* __restrict__ img,
                                                   const float* __restrict__ cam,
                                                   short* __restrict__ Xb,
                                                   const float* __restrict__ wqkv,
                                                   short* __restrict__ Wqkvt,
                                                   const float* __restrict__ wproj,
                                                   short* __restrict__ Wprojt) {
  __shared__ float tile[32][33];
  const int bid = blockIdx.x;
  if (bid < 4112) {
    int gt = bid * 256 + threadIdx.x;
    int e = gt << 2;                      // 4 floats per thread, exact cover of 4112*1024
    int row = e >> 10, col = e & 1023;
    int b = row / U_, u = row % U_, t = u / 257, jj = u % 257;
    const float* src = jj ? (img + ((size_t)((b * 8 + t) * 256 + (jj - 1)) << 10))
                          : (cam + ((size_t)(b * 8 + t) << 10));
    float4 f = *(const float4*)(src + col);
    s16x4 o;
    o[0] = f2bf(f.x); o[1] = f2bf(f.y); o[2] = f2bf(f.z); o[3] = f2bf(f.w);
    *(s16x4*)(Xb + ((size_t)row << 10) + col) = o;
    return;
  }
  const float* in; short* out; int Cc, bx, by;
  if (bid < 4112 + 3072) {
    int i = bid - 4112; bx = i % 96; by = i / 96; in = wqkv; out = Wqkvt; Cc = 3072;
  } else {
    int i = bid - 7184; bx = i % 32; by = i / 32; in = wproj; out = Wprojt; Cc = 1024;
  }
  constexpr int R = 1024;
  int tx = threadIdx.x & 31, ty = threadIdx.x >> 5;
  int col0 = bx << 5, row0 = by << 5;
#pragma unroll
  for (int i = 0; i < 4; i++) {
    int r = ty + i * 8;
    tile[r][tx] = in[(size_t)(row0 + r) * Cc + col0 + tx];
  }
  __syncthreads();
#pragma unroll
  for (int i = 0; i < 4; i++) {
    int r = ty + i * 8;
    out[(size_t)(col0 + r) * R + row0 + tx] = f2bf(tile[tx][r]);
  }
}

// ---------------- 128x128 bf16 GEMM, Bt is [N][K] row-major ----------------
// EPI 0: QKV epilogue (RoPE + q/k/v scatter).  EPI 1: proj epilogue (bias + out scatter).
template <int EPI>
__global__ __launch_bounds__(256) void gemm_kernel(
    const short* __restrict__ A, const short* __restrict__ Bt,
    const float* __restrict__ cosi, const float* __restrict__ sini,
    const float* __restrict__ cosc, const float* __restrict__ sinc,
    short* __restrict__ qb, short* __restrict__ kb, short* __restrict__ vb,
    const float* __restrict__ bias, float* __restrict__ outp) {
  constexpr int K = 1024;
  __shared__ __align__(16) short As[128 * 32];
  __shared__ __align__(16) short Bs[128 * 32];
  const int tid = threadIdx.x, w = tid >> 6, lane = tid & 63;
  const int l16 = lane & 15, quad = lane >> 4;
  const int bn = blockIdx.x, bm = blockIdx.y;
  const f32x4 zero = {0.f, 0.f, 0.f, 0.f};
  f32x4 acc[4][4];
#pragma unroll
  for (int i = 0; i < 4; i++)
#pragma unroll
    for (int j = 0; j < 4; j++) acc[i][j] = zero;

  const int mb = (w >> 1) << 6, nb = (w & 1) << 6;

  for (int kb0 = 0; kb0 < K; kb0 += 32) {
    __syncthreads();
#pragma unroll
    for (int i = 0; i < 2; i++) {
      int row = (w << 5) + (i << 4) + (lane >> 2);
      int cseg = (lane & 3) << 3;
      const short* ga = A + (size_t)(bm * 128 + row) * K + kb0 + cseg;
      char* la = (char*)As + ((w << 5) + (i << 4)) * 64 + lane * 16;
      ASYNC_COPY16(ga, la);
      const short* gb = Bt + (size_t)(bn * 128 + row) * K + kb0 + cseg;
      char* lb = (char*)Bs + ((w << 5) + (i << 4)) * 64 + lane * 16;
      ASYNC_COPY16(gb, lb);
    }
    __syncthreads();
    s16x8 af[4], bf[4];
#pragma unroll
    for (int mi = 0; mi < 4; mi++)
      af[mi] = *(const s16x8*)&As[(mb + mi * 16 + l16) * 32 + quad * 8];
#pragma unroll
    for (int ni = 0; ni < 4; ni++)
      bf[ni] = *(const s16x8*)&Bs[(nb + ni * 16 + l16) * 32 + quad * 8];
#pragma unroll
    for (int mi = 0; mi < 4; mi++)
#pragma unroll
      for (int ni = 0; ni < 4; ni++)
        acc[mi][ni] = __builtin_amdgcn_mfma_f32_16x16x32_bf16(af[mi], bf[ni], acc[mi][ni], 0, 0, 0);
  }

  // epilogue: C/D layout col = lane&15, row = quad*4 + reg
#pragma unroll
  for (int mi = 0; mi < 4; mi++) {
#pragma unroll
    for (int ni = 0; ni < 4; ni++) {
#pragma unroll
      for (int reg = 0; reg < 4; reg++) {
        float val = acc[mi][ni][reg];
        float partner = __shfl_xor(val, 1, 64);  // neighbor column (d^1), same row
        int R = bm * 128 + mb + mi * 16 + quad * 4 + reg;
        int Cg = bn * 128 + nb + ni * 16 + l16;
        int b = R / U_;
        if (b < 2) {
          int u = R % U_, t = u / 257, jj = u % 257;
          if constexpr (EPI == 0) {
            int which = Cg >> 10, hc = Cg & 1023, h = hc >> 6, d = hc & 63;
            int bh = b * 16 + h;
            if (which == 2) {
              vb[((size_t)bh * UPAD_ + u) * 64 + d] = f2bf(val);
            } else {
              const float *ct, *st; int pos;
              if (jj == 0) { ct = cosc; st = sinc; pos = t; }
              else         { ct = cosi; st = sini; pos = u - t - 1; }
              float cv = ct[pos * 64 + d], sv = st[pos * 64 + d];
              float o = val * cv + ((d & 1) ? partner : -partner) * sv;
              if (which == 0) {
                o *= 0.18033688f;  // fold 1/sqrt(64) * log2(e) into q (exp2-domain softmax)
                qb[((size_t)bh * U_ + u) * 64 + d] = f2bf(o);
              } else {
                kb[((size_t)bh * UPAD_ + u) * 64 + d] = f2bf(o);
              }
            }
          } else {
            float o = val + bias[Cg];
            if (jj) outp[(size_t)((b * 8 + t) * 256 + jj - 1) * 1024 + Cg] = o;
            else    outp[IMG_OUT_ELEMS + (size_t)(b * 8 + t) * 1024 + Cg] = o;
          }
        }
      }
    }
  }
}

// ---------------- fused flash attention (img queries only) ----------------
// grid: 1024 1-D blocks; XCD-aware decode (each XCD owns 4 bh -> K/V L2-resident).
// Swapped QK^T (T12): S^T = mfma(K_frag, Q_frag) -> each lane owns ONE q-row
// (q = l16) with 16 in-lane kv values -> softmax max/sum are in-lane + 2
// cross-lane ops per tile (vs 16 ds_swizzles in the unswapped form).
__global__ __launch_bounds__(256) void attn_kernel(const short* __restrict__ q,
                                                   const short* __restrict__ k,
                                                   const short* __restrict__ vt,
                                                   short* __restrict__ x) {
  __shared__ __align__(16) short Kt[64 * 64];      // [kv][d] XOR-swizzled
  __shared__ __align__(16) short Vt[64 * 64];      // [d][kv] XOR-swizzled
  __shared__ __align__(16) short Pt[4 * 16 * 72];  // per-wave [q][kv], stride 72
  const int tid = threadIdx.x, w = tid >> 6, lane = tid & 63;
  const int l16 = lane & 15, quad = lane >> 4;
  const int flat = blockIdx.x;
  const int slot = flat >> 3;
  const int bh = ((flat & 7) << 2) + (slot >> 5);
  const int qt = slot & 31;
  const int b = bh >> 4, h = bh & 15;

  // q rows: global img row g -> fused u = g + (g>>8) + 1
  const int g = qt * 64 + w * 16 + l16;
  const int u_q = g + (g >> 8) + 1;
  const short* qp = q + ((size_t)bh * U_ + u_q) * 64;
  const s16x8 aq0 = *(const s16x8*)(qp + quad * 8);
  const s16x8 aq1 = *(const s16x8*)(qp + 32 + quad * 8);

  // reg-staging geometry: lane stages rows sr and sr+32, 16B granule c8.
  // Global reads are linear; swizzle is applied on the ds_write side.
  const int sr = w * 8 + (lane >> 3);              // 0..31
  const int c8 = lane & 7;
  const short* kg = k + ((size_t)bh * UPAD_ + sr) * 64 + (c8 << 3);
  const short* vg = vt + ((size_t)bh * 64 + sr) * UPAD_ + (c8 << 3);
  const int swz = ((c8 ^ (sr & 7)) << 3);          // (sr+32)&7 == sr&7
  short* const wk0 = &Kt[sr * 64 + swz];
  short* const wk1 = &Kt[(sr + 32) * 64 + swz];
  short* const wv0 = &Vt[sr * 64 + swz];
  short* const wv1 = &Vt[(sr + 32) * 64 + swz];

  // swizzled LDS read columns (shorts); row = ni*16+l16 -> row&7 = l16&7
  const int cK0 = (quad * 8) ^ ((l16 & 7) << 3);
  const int cK1 = (32 + quad * 8) ^ ((l16 & 7) << 3);
  // Pt row = q = l16 (same row for write and read sides)
  short* const pw = Pt + (w * 16 + l16) * 72;

  const f32x4 zero = {0.f, 0.f, 0.f, 0.f};
  float m_r = -3e38f, l_r = 0.f;
  f32x4 o_acc[4];
#pragma unroll
  for (int r = 0; r < 4; r++) o_acc[r] = zero;

  // prologue: stage tile 0 into regs
  s16x8 rk0 = *(const s16x8*)(kg);
  s16x8 rk1 = *(const s16x8*)(kg + 2048);
  s16x8 rv0 = *(const s16x8*)(vg);
  s16x8 rv1 = *(const s16x8*)(vg + 32 * UPAD_);
  kg += 64 * 64;
  vg += 64;

  for (int kv0 = 0; kv0 < U_; kv0 += 64) {
    __syncthreads();                 // prev tile's LDS reads complete
    *(s16x8*)wk0 = rk0;
    *(s16x8*)wk1 = rk1;
    *(s16x8*)wv0 = rv0;
    *(s16x8*)wv1 = rv1;
    __syncthreads();                 // LDS ready
    if (kv0 + 64 < U_) {             // issue next-tile loads; hide under compute
      rk0 = *(const s16x8*)(kg);
      rk1 = *(const s16x8*)(kg + 2048);
      rv0 = *(const s16x8*)(vg);
      rv1 = *(const s16x8*)(vg + 32 * UPAD_);
      kg += 64 * 64;
      vg += 64;
    }

    // S^T = K Q^T: C row = kv (quad*4+reg within 16-block ni), col = q = l16
    f32x4 sT[4];
    __builtin_amdgcn_s_setprio(1);
#pragma unroll
    for (int ni = 0; ni < 4; ni++) {
      const s16x8 b0 = *(const s16x8*)&Kt[(ni * 16 + l16) * 64 + cK0];
      const s16x8 b1 = *(const s16x8*)&Kt[(ni * 16 + l16) * 64 + cK1];
      f32x4 z = __builtin_amdgcn_mfma_f32_16x16x32_bf16(b0, aq0, zero, 0, 0, 0);
      sT[ni] = __builtin_amdgcn_mfma_f32_16x16x32_bf16(b1, aq1, z, 0, 0, 0);
    }
    __builtin_amdgcn_s_setprio(0);

    // tail tile: real kv are 2048..2055 -> kv_local = ni*16+quad*4+reg < 8
    if (kv0 == 2048) {
#pragma unroll
      for (int ni = 0; ni < 4; ni++) {
        if (ni > 0 || quad >= 2) {
          sT[ni][0] = -1e30f; sT[ni][1] = -1e30f;
          sT[ni][2] = -1e30f; sT[ni][3] = -1e30f;
        }
      }
    }

    // online softmax, in-lane: row max over 16 values + 2 cross-lane ops
    float mx01 = fmaxf(fmaxf(sT[0][0], sT[0][1]), fmaxf(sT[0][2], sT[0][3]));
    float mx23 = fmaxf(fmaxf(sT[1][0], sT[1][1]), fmaxf(sT[1][2], sT[1][3]));
    float mx45 = fmaxf(fmaxf(sT[2][0], sT[2][1]), fmaxf(sT[2][2], sT[2][3]));
    float mx67 = fmaxf(fmaxf(sT[3][0], sT[3][1]), fmaxf(sT[3][2], sT[3][3]));
    float mx = fmaxf(fmaxf(mx01, mx23), fmaxf(mx45, mx67));
    mx = fmaxf(mx, __shfl_xor(mx, 16, 64));
    mx = fmaxf(mx, __shfl_xor(mx, 32, 64));

    // T13 defer-max: rescale only when max grew by >= 8 (exp2 domain)
    if (__any(mx > m_r + 8.f)) {
      const float mnew = fmaxf(m_r, mx);
      const float al = exp2a(m_r - mnew);
      m_r = mnew;
      l_r *= al;
      float aR[4];
#pragma unroll
      for (int reg = 0; reg < 4; reg++) aR[reg] = __shfl(al, quad * 4 + reg, 64);
#pragma unroll
      for (int ni = 0; ni < 4; ni++)
#pragma unroll
        for (int reg = 0; reg < 4; reg++) o_acc[ni][reg] *= aR[reg];
    }

    float rs = 0.f;
#pragma unroll
    for (int ni = 0; ni < 4; ni++)
#pragma unroll
      for (int reg = 0; reg < 4; reg++) {
        const float p = exp2a(sT[ni][reg] - m_r);
        sT[ni][reg] = p;
        rs += p;
      }
    l_r += rs;                       // per-lane partial; reduced at end

    // P -> Pt[q=l16][kv]: regs 0..3 are consecutive kv -> one b64 per ni
#pragma unroll
    for (int ni = 0; ni < 4; ni++) {
      uint2 pk;
      pk.x = cvt_pk_bf16(sT[ni][0], sT[ni][1]);
      pk.y = cvt_pk_bf16(sT[ni][2], sT[ni][3]);
      *(uint2*)&pw[ni * 16 + quad * 4] = pk;
    }

    // O += P V  (A-frag: P[q=l16][kv = ks*32 + quad*8 ..+7])
    __builtin_amdgcn_s_setprio(1);
#pragma unroll
    for (int ks = 0; ks < 2; ks++) {
      const s16x8 ap = *(const s16x8*)&pw[ks * 32 + quad * 8];
#pragma unroll
      for (int ni = 0; ni < 4; ni++) {
        const s16x8 bv = *(const s16x8*)&Vt[(ni * 16 + l16) * 64 + (ks ? cK1 : cK0)];
        o_acc[ni] = __builtin_amdgcn_mfma_f32_16x16x32_bf16(ap, bv, o_acc[ni], 0, 0, 0);
      }
    }
    __builtin_amdgcn_s_setprio(0);
  }

  // final l reduction across quads (same q = l16 in lanes l16, l16+16, +32, +48)
  l_r += __shfl_xor(l_r, 16, 64);
  l_r += __shfl_xor(l_r, 32, 64);
  const float linv = 1.f / l_r;
  float lR[4];
#pragma unroll
  for (int reg = 0; reg < 4; reg++) lR[reg] = __shfl(linv, quad * 4 + reg, 64);

  // write x[b*2056+u][h*64+d] bf16 (o row = q = quad*4+reg, col = ni*16+l16)
#pragma unroll
  for (int reg = 0; reg < 4; reg++) {
    const int go = qt * 64 + w * 16 + quad * 4 + reg;
    const int u_o = go + (go >> 8) + 1;
#pragma unroll
    for (int ni = 0; ni < 4; ni++)
      x[((size_t)(b * U_ + u_o)) * 1024 + h * 64 + ni * 16 + l16] =
          f2bf(o_acc[ni][reg] * lR[reg]);
  }
}

// ---------------- fused vt transpose + cam-query attention ----------------
// blocks 0..1055: bf16 v[bh][2112][64] -> vt[bh][64][2112] (zero pad rows)
// blocks 1056..1311: cam attention, one block per (t,bh), frame-causal.
__global__ __launch_bounds__(256) void vtcam_kernel(const short* __restrict__ v,
                                                    short* __restrict__ vt,
                                                    const short* __restrict__ q,
                                                    const short* __restrict__ k,
                                                    short* __restrict__ x) {
  __shared__ __align__(16) char smem[16448];
  const int bid = blockIdx.x;
  const int tid = threadIdx.x;
  if (bid < 1056) {
    short (*t2)[65] = (short(*)[65])smem;          // 64*65*2 = 8320 B
    int kt = bid % 33, bh = bid / 33;
#pragma unroll
    for (int i = 0; i < 16; i++) {
      int e = tid + i * 256; int r = e >> 6, c = e & 63;
      short vv = v[((size_t)bh * UPAD_ + kt * 64 + r) * 64 + c];
      t2[r][c] = (kt * 64 + r < U_) ? vv : (short)0;
    }
    __syncthreads();
#pragma unroll
    for (int i = 0; i < 16; i++) {
      int e = tid + i * 256; int d = e >> 6, c = e & 63;
      vt[((size_t)bh * 64 + d) * UPAD_ + kt * 64 + c] = t2[c][d];
    }
    return;
  }
  float* sb = (float*)smem;                        // 2056 floats
  float* red = sb + U_;                            // 8 floats
  float (*obuf)[64] = (float(*)[64])(red + 8);     // 32*64 floats
  const int i0 = bid - 1056;
  const int t = i0 & 7, bh = i0 >> 3;
  const int b = bh >> 4, h = bh & 15;
  const int L = (t + 1) * 257;
  const int lane = tid & 63, w = tid >> 6;
  const int u_q = t * 257;

  float qf[64];
  {
    const short* qpp = q + ((size_t)bh * U_ + u_q) * 64;
#pragma unroll
    for (int i = 0; i < 8; i++) {
      const s16x8 qv = *(const s16x8*)(qpp + i * 8);
#pragma unroll
      for (int j = 0; j < 8; j++) qf[i * 8 + j] = b2f(qv[j]);
    }
  }

  float lm = -3e38f;
  for (int kv = tid; kv < L; kv += 256) {
    const short* kp = k + ((size_t)bh * UPAD_ + kv) * 64;
    float s = 0.f;
#pragma unroll
    for (int i = 0; i < 8; i++) {
      const s16x8 kvv = *(const s16x8*)(kp + i * 8);
#pragma unroll
      for (int j = 0; j < 8; j++) s += qf[i * 8 + j] * b2f(kvv[j]);
    }
    sb[kv] = s;
    lm = fmaxf(lm, s);
  }
#pragma unroll
  for (int d = 1; d < 64; d <<= 1) lm = fmaxf(lm, __shfl_xor(lm, d, 64));
  if (lane == 0) red[w] = lm;
  __syncthreads();
  const float m = fmaxf(fmaxf(red[0], red[1]), fmaxf(red[2], red[3]));

  float ls = 0.f;
  for (int kv = tid; kv < L; kv += 256) {
    const float p = exp2a(sb[kv] - m);
    sb[kv] = p;
    ls += p;
  }
#pragma unroll
  for (int d = 1; d < 64; d <<= 1) ls += __shfl_xor(ls, d, 64);
  if (lane == 0) red[4 + w] = ls;
  __syncthreads();
  const float linv = 1.f / (red[4] + red[5] + red[6] + red[7]);

  const int d0 = (tid & 7) << 3;
  const int slot = tid >> 3;
  float acc[8];
#pragma unroll
  for (int j = 0; j < 8; j++) acc[j] = 0.f;
  for (int kv = slot; kv < L; kv += 32) {
    const float p = sb[kv];
    const s16x8 vv = *(const s16x8*)(v + ((size_t)bh * UPAD_ + kv) * 64 + d0);
#pragma unroll
    for (int j = 0; j < 8; j++) acc[j] += p * b2f(vv[j]);
  }
#pragma unroll
  for (int j = 0; j < 8; j++) obuf[slot][d0 + j] = acc[j];
  __syncthreads();
  if (tid < 64) {
    float s = 0.f;
#pragma unroll
    for (int i = 0; i < 32; i++) s += obuf[i][tid];
    x[((size_t)(b * U_ + u_q)) * 1024 + h * 64 + tid] = f2bf(s * linv);
  }
}

// ---------------- launch ----------------
extern "C" void kernel_launch(void* const* d_in, const int* in_sizes, int n_in,
                              void* d_out, int out_size, void* d_ws, size_t ws_size,
                              hipStream_t stream) {
  const float* img   = (const float*)d_in[0];
  const float* cam   = (const float*)d_in[1];
  const float* wqkv  = (const float*)d_in[2];
  const float* wproj = (const float*)d_in[3];
  const float* bias  = (const float*)d_in[4];
  const float* cosi  = (const float*)d_in[5];
  const float* sini  = (const float*)d_in[6];
  const float* cosc  = (const float*)d_in[7];
  const float* sinc  = (const float*)d_in[8];
  float* outp = (float*)d_out;

  char* ws = (char*)d_ws;
  short* Xb     = (short*)(ws + OFF_XB);
  short* Wqkvt  = (short*)(ws + OFF_WQKVT);
  short* Wprojt = (short*)(ws + OFF_WPROJT);
  short* qb     = (short*)(ws + OFF_Q);
  short* kb     = (short*)(ws + OFF_K);
  short* vb     = (short*)(ws + OFF_V);
  short* vtb    = (short*)(ws + OFF_VT);
  short* xb     = (short*)(ws + OFF_X);

  prep_kernel<<<8208, 256, 0, stream>>>(img, cam, Xb, wqkv, Wqkvt, wproj, Wprojt);
  gemm_kernel<0><<<dim3(24, 33), 256, 0, stream>>>(Xb, Wqkvt, cosi, sini, cosc, sinc,
                                                   qb, kb, vb, nullptr, nullptr);
  vtcam_kernel<<<1312, 256, 0, stream>>>(vb, vtb, qb, kb, xb);
  attn_kernel<<<1024, 256, 0, stream>>>(qb, kb, vtb, xb);
  gemm_kernel<1><<<dim3(8, 33), 256, 0, stream>>>(xb, Wprojt, nullptr, nullptr, nullptr, nullptr,
                                                  nullptr, nullptr, nullptr, bias, outp);
}

// Round 4
// 289.048 us; speedup vs baseline: 1.3045x; 1.0812x over previous
//
#include <hip/hip_runtime.h>

// ---------------- problem constants ----------------
#define T_ 8
#define N_ 256
#define C_ 1024
#define H_ 16
#define D_ 64
#define U_ 2056      // fused tokens per batch = T*(N+1)
#define UPAD_ 2112   // 33*64
#define MROWS_ 4112  // B*U
#define MPAD_ 4224   // 33*128
#define IMG_OUT_ELEMS 4194304  // 2*8*256*1024

typedef __attribute__((ext_vector_type(4))) float f32x4;
typedef __attribute__((ext_vector_type(8))) short s16x8;
typedef __attribute__((ext_vector_type(4))) short s16x4;

__device__ __forceinline__ short f2bf(float f) {
  union { float f; unsigned u; } a; a.f = f;
  unsigned u = a.u;
  return (short)((u + 0x7fffu + ((u >> 16) & 1u)) >> 16);
}

__device__ __forceinline__ float b2f(short s) {
  union { unsigned u; float f; } a;
  a.u = ((unsigned)(unsigned short)s) << 16;
  return a.f;
}

// bare v_exp_f32 (2^x). q is pre-scaled by log2(e) so softmax runs in exp2 domain.
__device__ __forceinline__ float exp2a(float x) {
  float r; asm("v_exp_f32 %0, %1" : "=v"(r) : "v"(x)); return r;
}

__device__ __forceinline__ unsigned cvt_pk_bf16(float lo, float hi) {
  unsigned r; asm("v_cvt_pk_bf16_f32 %0, %1, %2" : "=v"(r) : "v"(lo), "v"(hi)); return r;
}

#define ASYNC_COPY16(gp, lp)                                                   \
  __builtin_amdgcn_global_load_lds((const __attribute__((address_space(1))) void*)(gp), \
                                   (__attribute__((address_space(3))) void*)(lp), 16, 0, 0)

// ---------------- workspace offsets (bytes) ----------------
constexpr size_t OFF_XB     = 0;                         // 4224*1024*2
constexpr size_t OFF_WQKVT  = OFF_XB + 8650752;          // 3072*1024*2
constexpr size_t OFF_WPROJT = OFF_WQKVT + 6291456;       // 1024*1024*2
constexpr size_t OFF_Q      = OFF_WPROJT + 2097152;      // 32*2056*64*2
constexpr size_t OFF_K      = OFF_Q + 8421376;           // 32*2112*64*2
constexpr size_t OFF_V      = OFF_K + 8650752;           // 32*2112*64*2
constexpr size_t OFF_VT     = OFF_V + 8650752;           // 32*64*2112*2
constexpr size_t OFF_X      = OFF_VT + 8650752;          // 4224*1024*2
// total ~60 MB

// ---------------- fused prep: pack X + both weight transposes ----------------
__global__ __launch_bounds__(256) void prep_kernel(const float* __restrict__ img,
                                                   const float* __restrict__ cam,
                                                   short* __restrict__ Xb,
                                                   const float* __restrict__ wqkv,
                                                   short* __restrict__ Wqkvt,
                                                   const float* __restrict__ wproj,
                                                   short* __restrict__ Wprojt) {
  __shared__ float tile[32][33];
  const int bid = blockIdx.x;
  if (bid < 4112) {
    int gt = bid * 256 + threadIdx.x;
    int e = gt << 2;                      // 4 floats per thread, exact cover of 4112*1024
    int row = e >> 10, col = e & 1023;
    int b = row / U_, u = row % U_, t = u / 257, jj = u % 257;
    const float* src = jj ? (img + ((size_t)((b * 8 + t) * 256 + (jj - 1)) << 10))
                          : (cam + ((size_t)(b * 8 + t) << 10));
    float4 f = *(const float4*)(src + col);
    s16x4 o;
    o[0] = f2bf(f.x); o[1] = f2bf(f.y); o[2] = f2bf(f.z); o[3] = f2bf(f.w);
    *(s16x4*)(Xb + ((size_t)row << 10) + col) = o;
    return;
  }
  const float* in; short* out; int Cc, bx, by;
  if (bid < 4112 + 3072) {
    int i = bid - 4112; bx = i % 96; by = i / 96; in = wqkv; out = Wqkvt; Cc = 3072;
  } else {
    int i = bid - 7184; bx = i % 32; by = i / 32; in = wproj; out = Wprojt; Cc = 1024;
  }
  constexpr int R = 1024;
  int tx = threadIdx.x & 31, ty = threadIdx.x >> 5;
  int col0 = bx << 5, row0 = by << 5;
#pragma unroll
  for (int i = 0; i < 4; i++) {
    int r = ty + i * 8;
    tile[r][tx] = in[(size_t)(row0 + r) * Cc + col0 + tx];
  }
  __syncthreads();
#pragma unroll
  for (int i = 0; i < 4; i++) {
    int r = ty + i * 8;
    out[(size_t)(col0 + r) * R + row0 + tx] = f2bf(tile[tx][r]);
  }
}

// ---------------- 128x128 bf16 GEMM, Bt is [N][K] row-major ----------------
// Double-buffered LDS; stage(t+1) issues right after the barrier and drains at
// the NEXT barrier (T3 minimum 2-phase) -> load latency hides under MFMA.
// 1-D grid with XCD-chunked decode (each XCD owns a contiguous bn range).
// EPI 0: QKV epilogue (RoPE + q/k/v scatter).  EPI 1: proj epilogue (bias + out).
template <int EPI>
__global__ __launch_bounds__(256) void gemm_kernel(
    const short* __restrict__ A, const short* __restrict__ Bt,
    const float* __restrict__ cosi, const float* __restrict__ sini,
    const float* __restrict__ cosc, const float* __restrict__ sinc,
    short* __restrict__ qb, short* __restrict__ kb, short* __restrict__ vb,
    const float* __restrict__ bias, float* __restrict__ outp) {
  constexpr int K = 1024;
  __shared__ __align__(16) short As[2][128 * 32];
  __shared__ __align__(16) short Bs[2][128 * 32];
  const int tid = threadIdx.x, w = tid >> 6, lane = tid & 63;
  const int l16 = lane & 15, quad = lane >> 4;

  int bn, bm;
  {
    const int flat = blockIdx.x;
    const int xcd = flat & 7, idx = flat >> 3;
    if constexpr (EPI == 0) { bn = xcd * 3 + idx / 33; bm = idx % 33; }   // 792 blocks
    else                    { bn = xcd;                bm = idx;       }  // 264 blocks
  }

  const f32x4 zero = {0.f, 0.f, 0.f, 0.f};
  f32x4 acc[4][4];
#pragma unroll
  for (int i = 0; i < 4; i++)
#pragma unroll
    for (int j = 0; j < 4; j++) acc[i][j] = zero;

  const int mb = (w >> 1) << 6, nb = (w & 1) << 6;

  // staging geometry (per wave covers 2x16 rows; lane -> row=lane>>2, granule=lane&3)
  const int srow = (w << 5) + (lane >> 2);
  const int cseg = (lane & 3) << 3;
  const short* gA = A + (size_t)(bm * 128 + srow) * K + cseg;
  const short* gB = Bt + (size_t)(bn * 128 + srow) * K + cseg;
  const int lo0 = ((w << 5) << 6) + lane * 16;       // bytes within a buffer
  const int lo1 = lo0 + (16 << 6);

#define STAGE(buf, kb0)                                                        \
  do {                                                                         \
    ASYNC_COPY16(gA + (kb0), (char*)As[buf] + lo0);                            \
    ASYNC_COPY16(gA + (size_t)16 * K + (kb0), (char*)As[buf] + lo1);           \
    ASYNC_COPY16(gB + (kb0), (char*)Bs[buf] + lo0);                            \
    ASYNC_COPY16(gB + (size_t)16 * K + (kb0), (char*)Bs[buf] + lo1);           \
  } while (0)

  STAGE(0, 0);
  int cur = 0;
  for (int kb0 = 0; kb0 < K; kb0 += 32) {
    __syncthreads();                 // drains vmcnt -> buf[cur] ready; prev reads done
    if (kb0 + 32 < K) STAGE(cur ^ 1, kb0 + 32);   // prefetch flies under compute
    s16x8 af[4], bf[4];
#pragma unroll
    for (int mi = 0; mi < 4; mi++)
      af[mi] = *(const s16x8*)&As[cur][(mb + mi * 16 + l16) * 32 + quad * 8];
#pragma unroll
    for (int ni = 0; ni < 4; ni++)
      bf[ni] = *(const s16x8*)&Bs[cur][(nb + ni * 16 + l16) * 32 + quad * 8];
#pragma unroll
    for (int mi = 0; mi < 4; mi++)
#pragma unroll
      for (int ni = 0; ni < 4; ni++)
        acc[mi][ni] = __builtin_amdgcn_mfma_f32_16x16x32_bf16(af[mi], bf[ni], acc[mi][ni], 0, 0, 0);
    cur ^= 1;
  }
#undef STAGE

  // epilogue: C/D layout col = lane&15, row = quad*4 + reg
  if constexpr (EPI == 0) {
    const int cbase = bn * 128 + nb;          // wave-uniform, multiple of 64
    const int which = cbase >> 10;            // 0=q 1=k 2=v (64-col blocks never cross)
    const int hh = (cbase & 1023) >> 6;       // head, wave-uniform; d = ni*16+l16
#pragma unroll
    for (int mi = 0; mi < 4; mi++) {
#pragma unroll
      for (int reg = 0; reg < 4; reg++) {
        const int R = bm * 128 + mb + mi * 16 + quad * 4 + reg;
        if (R < MROWS_) {
          const int b = (R >= U_) ? 1 : 0;
          const int u = R - b * U_;
          const int t = (u - (u >> 8)) >> 8;  // u/257 for u<2056
          const int jj = u - ((t << 8) + t);
          const int bh = b * 16 + hh;
          if (which == 2) {
#pragma unroll
            for (int ni = 0; ni < 4; ni++)
              vb[((size_t)bh * UPAD_ + u) * 64 + ni * 16 + l16] = f2bf(acc[mi][ni][reg]);
          } else {
            const float *ct, *st; int pos;
            if (jj == 0) { ct = cosc; st = sinc; pos = t; }
            else         { ct = cosi; st = sini; pos = u - t - 1; }
#pragma unroll
            for (int ni = 0; ni < 4; ni++) {
              const int d = ni * 16 + l16;
              const float val = acc[mi][ni][reg];
              const float partner = __shfl_xor(val, 1, 64);  // d^1 neighbor, same row
              const float cv = ct[pos * 64 + d], sv = st[pos * 64 + d];
              float o = val * cv + ((d & 1) ? partner : -partner) * sv;
              if (which == 0) {
                o *= 0.18033688f;  // fold 1/sqrt(64) * log2(e) into q (exp2-domain softmax)
                qb[((size_t)bh * U_ + u) * 64 + d] = f2bf(o);
              } else {
                kb[((size_t)bh * UPAD_ + u) * 64 + d] = f2bf(o);
              }
            }
          }
        }
      }
    }
  } else {
    const int cbase = bn * 128 + nb;
#pragma unroll
    for (int mi = 0; mi < 4; mi++) {
#pragma unroll
      for (int reg = 0; reg < 4; reg++) {
        const int R = bm * 128 + mb + mi * 16 + quad * 4 + reg;
        if (R < MROWS_) {
          const int b = (R >= U_) ? 1 : 0;
          const int u = R - b * U_;
          const int t = (u - (u >> 8)) >> 8;
          const int jj = u - ((t << 8) + t);
          size_t rowoff;
          if (jj) rowoff = (size_t)((b * 8 + t) * 256 + jj - 1) * 1024;
          else    rowoff = IMG_OUT_ELEMS + (size_t)(b * 8 + t) * 1024;
#pragma unroll
          for (int ni = 0; ni < 4; ni++) {
            const int Cg = cbase + ni * 16 + l16;
            outp[rowoff + Cg] = acc[mi][ni][reg] + bias[Cg];
          }
        }
      }
    }
  }
}

// ---------------- fused flash attention (img queries only) ----------------
// grid: 1024 1-D blocks; XCD-aware decode (each XCD owns 4 bh -> K/V L2-resident).
// Swapped QK^T (T12): S^T = mfma(K_frag, Q_frag) -> each lane owns ONE q-row
// (q = l16) with 16 in-lane kv values -> softmax max/sum are in-lane + 2
// cross-lane ops per tile.
__global__ __launch_bounds__(256) void attn_kernel(const short* __restrict__ q,
                                                   const short* __restrict__ k,
                                                   const short* __restrict__ vt,
                                                   short* __restrict__ x) {
  __shared__ __align__(16) short Kt[64 * 64];      // [kv][d] XOR-swizzled
  __shared__ __align__(16) short Vt[64 * 64];      // [d][kv] XOR-swizzled
  __shared__ __align__(16) short Pt[4 * 16 * 72];  // per-wave [q][kv], stride 72
  const int tid = threadIdx.x, w = tid >> 6, lane = tid & 63;
  const int l16 = lane & 15, quad = lane >> 4;
  const int flat = blockIdx.x;
  const int slot = flat >> 3;
  const int bh = ((flat & 7) << 2) + (slot >> 5);
  const int qt = slot & 31;
  const int b = bh >> 4, h = bh & 15;

  // q rows: global img row g -> fused u = g + (g>>8) + 1
  const int g = qt * 64 + w * 16 + l16;
  const int u_q = g + (g >> 8) + 1;
  const short* qp = q + ((size_t)bh * U_ + u_q) * 64;
  const s16x8 aq0 = *(const s16x8*)(qp + quad * 8);
  const s16x8 aq1 = *(const s16x8*)(qp + 32 + quad * 8);

  // reg-staging geometry: lane stages rows sr and sr+32, 16B granule c8.
  const int sr = w * 8 + (lane >> 3);              // 0..31
  const int c8 = lane & 7;
  const short* kg = k + ((size_t)bh * UPAD_ + sr) * 64 + (c8 << 3);
  const short* vg = vt + ((size_t)bh * 64 + sr) * UPAD_ + (c8 << 3);
  const int swz = ((c8 ^ (sr & 7)) << 3);          // (sr+32)&7 == sr&7
  short* const wk0 = &Kt[sr * 64 + swz];
  short* const wk1 = &Kt[(sr + 32) * 64 + swz];
  short* const wv0 = &Vt[sr * 64 + swz];
  short* const wv1 = &Vt[(sr + 32) * 64 + swz];

  // swizzled LDS read columns (shorts); row = ni*16+l16 -> row&7 = l16&7
  const int cK0 = (quad * 8) ^ ((l16 & 7) << 3);
  const int cK1 = (32 + quad * 8) ^ ((l16 & 7) << 3);
  short* const pw = Pt + (w * 16 + l16) * 72;

  const f32x4 zero = {0.f, 0.f, 0.f, 0.f};
  float m_r = -3e38f, l_r = 0.f;
  f32x4 o_acc[4];
#pragma unroll
  for (int r = 0; r < 4; r++) o_acc[r] = zero;

  // prologue: stage tile 0 into regs
  s16x8 rk0 = *(const s16x8*)(kg);
  s16x8 rk1 = *(const s16x8*)(kg + 2048);
  s16x8 rv0 = *(const s16x8*)(vg);
  s16x8 rv1 = *(const s16x8*)(vg + 32 * UPAD_);
  kg += 64 * 64;
  vg += 64;

  for (int kv0 = 0; kv0 < U_; kv0 += 64) {
    __syncthreads();                 // prev tile's LDS reads complete
    *(s16x8*)wk0 = rk0;
    *(s16x8*)wk1 = rk1;
    *(s16x8*)wv0 = rv0;
    *(s16x8*)wv1 = rv1;
    __syncthreads();                 // LDS ready
    if (kv0 + 64 < U_) {             // issue next-tile loads; hide under compute
      rk0 = *(const s16x8*)(kg);
      rk1 = *(const s16x8*)(kg + 2048);
      rv0 = *(const s16x8*)(vg);
      rv1 = *(const s16x8*)(vg + 32 * UPAD_);
      kg += 64 * 64;
      vg += 64;
    }

    // S^T = K Q^T: C row = kv (quad*4+reg within 16-block ni), col = q = l16
    f32x4 sT[4];
    __builtin_amdgcn_s_setprio(1);
#pragma unroll
    for (int ni = 0; ni < 4; ni++) {
      const s16x8 b0 = *(const s16x8*)&Kt[(ni * 16 + l16) * 64 + cK0];
      const s16x8 b1 = *(const s16x8*)&Kt[(ni * 16 + l16) * 64 + cK1];
      f32x4 z = __builtin_amdgcn_mfma_f32_16x16x32_bf16(b0, aq0, zero, 0, 0, 0);
      sT[ni] = __builtin_amdgcn_mfma_f32_16x16x32_bf16(b1, aq1, z, 0, 0, 0);
    }
    __builtin_amdgcn_s_setprio(0);

    // tail tile: real kv are 2048..2055 -> kv_local = ni*16+quad*4+reg < 8
    if (kv0 == 2048) {
#pragma unroll
      for (int ni = 0; ni < 4; ni++) {
        if (ni > 0 || quad >= 2) {
          sT[ni][0] = -1e30f; sT[ni][1] = -1e30f;
          sT[ni][2] = -1e30f; sT[ni][3] = -1e30f;
        }
      }
    }

    // online softmax, in-lane: row max over 16 values + 2 cross-lane ops
    float mx01 = fmaxf(fmaxf(sT[0][0], sT[0][1]), fmaxf(sT[0][2], sT[0][3]));
    float mx23 = fmaxf(fmaxf(sT[1][0], sT[1][1]), fmaxf(sT[1][2], sT[1][3]));
    float mx45 = fmaxf(fmaxf(sT[2][0], sT[2][1]), fmaxf(sT[2][2], sT[2][3]));
    float mx67 = fmaxf(fmaxf(sT[3][0], sT[3][1]), fmaxf(sT[3][2], sT[3][3]));
    float mx = fmaxf(fmaxf(mx01, mx23), fmaxf(mx45, mx67));
    mx = fmaxf(mx, __shfl_xor(mx, 16, 64));
    mx = fmaxf(mx, __shfl_xor(mx, 32, 64));

    // T13 defer-max: rescale only when max grew by >= 8 (exp2 domain)
    if (__any(mx > m_r + 8.f)) {
      const float mnew = fmaxf(m_r, mx);
      const float al = exp2a(m_r - mnew);
      m_r = mnew;
      l_r *= al;
      float aR[4];
#pragma unroll
      for (int reg = 0; reg < 4; reg++) aR[reg] = __shfl(al, quad * 4 + reg, 64);
#pragma unroll
      for (int ni = 0; ni < 4; ni++)
#pragma unroll
        for (int reg = 0; reg < 4; reg++) o_acc[ni][reg] *= aR[reg];
    }

    float rs = 0.f;
#pragma unroll
    for (int ni = 0; ni < 4; ni++)
#pragma unroll
      for (int reg = 0; reg < 4; reg++) {
        const float p = exp2a(sT[ni][reg] - m_r);
        sT[ni][reg] = p;
        rs += p;
      }
    l_r += rs;                       // per-lane partial; reduced at end

    // P -> Pt[q=l16][kv]: regs 0..3 are consecutive kv -> one b64 per ni
#pragma unroll
    for (int ni = 0; ni < 4; ni++) {
      uint2 pk;
      pk.x = cvt_pk_bf16(sT[ni][0], sT[ni][1]);
      pk.y = cvt_pk_bf16(sT[ni][2], sT[ni][3]);
      *(uint2*)&pw[ni * 16 + quad * 4] = pk;
    }

    // O += P V  (A-frag: P[q=l16][kv = ks*32 + quad*8 ..+7])
    __builtin_amdgcn_s_setprio(1);
#pragma unroll
    for (int ks = 0; ks < 2; ks++) {
      const s16x8 ap = *(const s16x8*)&pw[ks * 32 + quad * 8];
#pragma unroll
      for (int ni = 0; ni < 4; ni++) {
        const s16x8 bv = *(const s16x8*)&Vt[(ni * 16 + l16) * 64 + (ks ? cK1 : cK0)];
        o_acc[ni] = __builtin_amdgcn_mfma_f32_16x16x32_bf16(ap, bv, o_acc[ni], 0, 0, 0);
      }
    }
    __builtin_amdgcn_s_setprio(0);
  }

  // final l reduction across quads (same q = l16 in lanes l16, l16+16, +32, +48)
  l_r += __shfl_xor(l_r, 16, 64);
  l_r += __shfl_xor(l_r, 32, 64);
  const float linv = 1.f / l_r;
  float lR[4];
#pragma unroll
  for (int reg = 0; reg < 4; reg++) lR[reg] = __shfl(linv, quad * 4 + reg, 64);

  // write x[b*2056+u][h*64+d] bf16 (o row = q = quad*4+reg, col = ni*16+l16)
#pragma unroll
  for (int reg = 0; reg < 4; reg++) {
    const int go = qt * 64 + w * 16 + quad * 4 + reg;
    const int u_o = go + (go >> 8) + 1;
#pragma unroll
    for (int ni = 0; ni < 4; ni++)
      x[((size_t)(b * U_ + u_o)) * 1024 + h * 64 + ni * 16 + l16] =
          f2bf(o_acc[ni][reg] * lR[reg]);
  }
}

// ---------------- fused vt transpose + cam-query attention ----------------
__global__ __launch_bounds__(256) void vtcam_kernel(const short* __restrict__ v,
                                                    short* __restrict__ vt,
                                                    const short* __restrict__ q,
                                                    const short* __restrict__ k,
                                                    short* __restrict__ x) {
  __shared__ __align__(16) char smem[16448];
  const int bid = blockIdx.x;
  const int tid = threadIdx.x;
  if (bid < 1056) {
    short (*t2)[65] = (short(*)[65])smem;          // 64*65*2 = 8320 B
    int kt = bid % 33, bh = bid / 33;
#pragma unroll
    for (int i = 0; i < 16; i++) {
      int e = tid + i * 256; int r = e >> 6, c = e & 63;
      short vv = v[((size_t)bh * UPAD_ + kt * 64 + r) * 64 + c];
      t2[r][c] = (kt * 64 + r < U_) ? vv : (short)0;
    }
    __syncthreads();
#pragma unroll
    for (int i = 0; i < 16; i++) {
      int e = tid + i * 256; int d = e >> 6, c = e & 63;
      vt[((size_t)bh * 64 + d) * UPAD_ + kt * 64 + c] = t2[c][d];
    }
    return;
  }
  float* sb = (float*)smem;                        // 2056 floats
  float* red = sb + U_;                            // 8 floats
  float (*obuf)[64] = (float(*)[64])(red + 8);     // 32*64 floats
  const int i0 = bid - 1056;
  const int t = i0 & 7, bh = i0 >> 3;
  const int b = bh >> 4, h = bh & 15;
  const int L = (t + 1) * 257;
  const int lane = tid & 63, w = tid >> 6;
  const int u_q = t * 257;

  float qf[64];
  {
    const short* qpp = q + ((size_t)bh * U_ + u_q) * 64;
#pragma unroll
    for (int i = 0; i < 8; i++) {
      const s16x8 qv = *(const s16x8*)(qpp + i * 8);
#pragma unroll
      for (int j = 0; j < 8; j++) qf[i * 8 + j] = b2f(qv[j]);
    }
  }

  float lm = -3e38f;
  for (int kv = tid; kv < L; kv += 256) {
    const short* kp = k + ((size_t)bh * UPAD_ + kv) * 64;
    float s = 0.f;
#pragma unroll
    for (int i = 0; i < 8; i++) {
      const s16x8 kvv = *(const s16x8*)(kp + i * 8);
#pragma unroll
      for (int j = 0; j < 8; j++) s += qf[i * 8 + j] * b2f(kvv[j]);
    }
    sb[kv] = s;
    lm = fmaxf(lm, s);
  }
#pragma unroll
  for (int d = 1; d < 64; d <<= 1) lm = fmaxf(lm, __shfl_xor(lm, d, 64));
  if (lane == 0) red[w] = lm;
  __syncthreads();
  const float m = fmaxf(fmaxf(red[0], red[1]), fmaxf(red[2], red[3]));

  float ls = 0.f;
  for (int kv = tid; kv < L; kv += 256) {
    const float p = exp2a(sb[kv] - m);
    sb[kv] = p;
    ls += p;
  }
#pragma unroll
  for (int d = 1; d < 64; d <<= 1) ls += __shfl_xor(ls, d, 64);
  if (lane == 0) red[4 + w] = ls;
  __syncthreads();
  const float linv = 1.f / (red[4] + red[5] + red[6] + red[7]);

  const int d0 = (tid & 7) << 3;
  const int slot = tid >> 3;
  float acc[8];
#pragma unroll
  for (int j = 0; j < 8; j++) acc[j] = 0.f;
  for (int kv = slot; kv < L; kv += 32) {
    const float p = sb[kv];
    const s16x8 vv = *(const s16x8*)(v + ((size_t)bh * UPAD_ + kv) * 64 + d0);
#pragma unroll
    for (int j = 0; j < 8; j++) acc[j] += p * b2f(vv[j]);
  }
#pragma unroll
  for (int j = 0; j < 8; j++) obuf[slot][d0 + j] = acc[j];
  __syncthreads();
  if (tid < 64) {
    float s = 0.f;
#pragma unroll
    for (int i = 0; i < 32; i++) s += obuf[i][tid];
    x[((size_t)(b * U_ + u_q)) * 1024 + h * 64 + tid] = f2bf(s * linv);
  }
}

// ---------------- launch ----------------
extern "C" void kernel_launch(void* const* d_in, const int* in_sizes, int n_in,
                              void* d_out, int out_size, void* d_ws, size_t ws_size,
                              hipStream_t stream) {
  const float* img   = (const float*)d_in[0];
  const float* cam   = (const float*)d_in[1];
  const float* wqkv  = (const float*)d_in[2];
  const float* wproj = (const float*)d_in[3];
  const float* bias  = (const float*)d_in[4];
  const float* cosi  = (const float*)d_in[5];
  const float* sini  = (const float*)d_in[6];
  const float* cosc  = (const float*)d_in[7];
  const float* sinc  = (const float*)d_in[8];
  float* outp = (float*)d_out;

  char* ws = (char*)d_ws;
  short* Xb     = (short*)(ws + OFF_XB);
  short* Wqkvt  = (short*)(ws + OFF_WQKVT);
  short* Wprojt = (short*)(ws + OFF_WPROJT);
  short* qb     = (short*)(ws + OFF_Q);
  short* kb     = (short*)(ws + OFF_K);
  short* vb     = (short*)(ws + OFF_V);
  short* vtb    = (short*)(ws + OFF_VT);
  short* xb     = (short*)(ws + OFF_X);

  prep_kernel<<<8208, 256, 0, stream>>>(img, cam, Xb, wqkv, Wqkvt, wproj, Wprojt);
  gemm_kernel<0><<<792, 256, 0, stream>>>(Xb, Wqkvt, cosi, sini, cosc, sinc,
                                          qb, kb, vb, nullptr, nullptr);
  vtcam_kernel<<<1312, 256, 0, stream>>>(vb, vtb, qb, kb, xb);
  attn_kernel<<<1024, 256, 0, stream>>>(qb, kb, vtb, xb);
  gemm_kernel<1><<<264, 256, 0, stream>>>(xb, Wprojt, nullptr, nullptr, nullptr, nullptr,
                                          nullptr, nullptr, nullptr, bias, outp);
}

// Round 7
// 272.579 us; speedup vs baseline: 1.3834x; 1.0604x over previous
//
#include <hip/hip_runtime.h>

// ---------------- problem constants ----------------
#define T_ 8
#define N_ 256
#define C_ 1024
#define H_ 16
#define D_ 64
#define U_ 2056      // fused tokens per batch = T*(N+1)
#define UPAD_ 2112   // 33*64
#define MROWS_ 4112  // B*U
#define MPAD_ 4224   // 33*128
#define IMG_OUT_ELEMS 4194304  // 2*8*256*1024

typedef __attribute__((ext_vector_type(4))) float f32x4;
typedef __attribute__((ext_vector_type(8))) short s16x8;
typedef __attribute__((ext_vector_type(4))) short s16x4;

__device__ __forceinline__ short f2bf(float f) {
  union { float f; unsigned u; } a; a.f = f;
  unsigned u = a.u;
  return (short)((u + 0x7fffu + ((u >> 16) & 1u)) >> 16);
}

__device__ __forceinline__ float b2f(short s) {
  union { unsigned u; float f; } a;
  a.u = ((unsigned)(unsigned short)s) << 16;
  return a.f;
}

// bare v_exp_f32 (2^x). q is pre-scaled by log2(e) so softmax runs in exp2 domain.
__device__ __forceinline__ float exp2a(float x) {
  float r; asm("v_exp_f32 %0, %1" : "=v"(r) : "v"(x)); return r;
}

__device__ __forceinline__ unsigned cvt_pk_bf16(float lo, float hi) {
  unsigned r; asm("v_cvt_pk_bf16_f32 %0, %1, %2" : "=v"(r) : "v"(lo), "v"(hi)); return r;
}

#define ASYNC_COPY16(gp, lp)                                                   \
  __builtin_amdgcn_global_load_lds((const __attribute__((address_space(1))) void*)(gp), \
                                   (__attribute__((address_space(3))) void*)(lp), 16, 0, 0)

// ---------------- workspace offsets (bytes) ----------------
constexpr size_t OFF_XB     = 0;                         // 4224*1024*2
constexpr size_t OFF_WQKVT  = OFF_XB + 8650752;          // 3072*1024*2
constexpr size_t OFF_WPROJT = OFF_WQKVT + 6291456;       // 1024*1024*2
constexpr size_t OFF_Q      = OFF_WPROJT + 2097152;      // 32*2056*64*2
constexpr size_t OFF_K      = OFF_Q + 8421376;           // 32*2112*64*2
constexpr size_t OFF_V      = OFF_K + 8650752;           // 32*2112*64*2
constexpr size_t OFF_VT     = OFF_V + 8650752;           // 32*64*2112*2
constexpr size_t OFF_X      = OFF_VT + 8650752;          // 4224*1024*2
// total ~60 MB

// ---------------- fused prep: pack X + both weight transposes ----------------
__global__ __launch_bounds__(256) void prep_kernel(const float* __restrict__ img,
                                                   const float* __restrict__ cam,
                                                   short* __restrict__ Xb,
                                                   const float* __restrict__ wqkv,
                                                   short* __restrict__ Wqkvt,
                                                   const float* __restrict__ wproj,
                                                   short* __restrict__ Wprojt) {
  __shared__ float tile[32][33];
  const int bid = blockIdx.x;
  if (bid < 4112) {
    int gt = bid * 256 + threadIdx.x;
    int e = gt << 2;                      // 4 floats per thread, exact cover of 4112*1024
    int row = e >> 10, col = e & 1023;
    int b = row / U_, u = row % U_, t = u / 257, jj = u % 257;
    const float* src = jj ? (img + ((size_t)((b * 8 + t) * 256 + (jj - 1)) << 10))
                          : (cam + ((size_t)(b * 8 + t) << 10));
    float4 f = *(const float4*)(src + col);
    s16x4 o;
    o[0] = f2bf(f.x); o[1] = f2bf(f.y); o[2] = f2bf(f.z); o[3] = f2bf(f.w);
    *(s16x4*)(Xb + ((size_t)row << 10) + col) = o;
    return;
  }
  const float* in; short* out; int Cc, bx, by;
  if (bid < 4112 + 3072) {
    int i = bid - 4112; bx = i % 96; by = i / 96; in = wqkv; out = Wqkvt; Cc = 3072;
  } else {
    int i = bid - 7184; bx = i % 32; by = i / 32; in = wproj; out = Wprojt; Cc = 1024;
  }
  constexpr int R = 1024;
  int tx = threadIdx.x & 31, ty = threadIdx.x >> 5;
  int col0 = bx << 5, row0 = by << 5;
#pragma unroll
  for (int i = 0; i < 4; i++) {
    int r = ty + i * 8;
    tile[r][tx] = in[(size_t)(row0 + r) * Cc + col0 + tx];
  }
  __syncthreads();
#pragma unroll
  for (int i = 0; i < 4; i++) {
    int r = ty + i * 8;
    out[(size_t)(col0 + r) * R + row0 + tx] = f2bf(tile[tx][r]);
  }
}

// ---------------- 128x128 bf16 GEMM, Bt is [N][K] row-major ----------------
// Double-buffered LDS; prefetch-after-barrier (T3 minimum 2-phase).
// 1-D grid, XCD-chunked decode.  EPI 0: QKV+RoPE.  EPI 1: proj+bias.
template <int EPI>
__global__ __launch_bounds__(256) void gemm_kernel(
    const short* __restrict__ A, const short* __restrict__ Bt,
    const float* __restrict__ cosi, const float* __restrict__ sini,
    const float* __restrict__ cosc, const float* __restrict__ sinc,
    short* __restrict__ qb, short* __restrict__ kb, short* __restrict__ vb,
    const float* __restrict__ bias, float* __restrict__ outp) {
  constexpr int K = 1024;
  __shared__ __align__(16) short As[2][128 * 32];
  __shared__ __align__(16) short Bs[2][128 * 32];
  const int tid = threadIdx.x, w = tid >> 6, lane = tid & 63;
  const int l16 = lane & 15, quad = lane >> 4;

  int bn, bm;
  {
    const int flat = blockIdx.x;
    const int xcd = flat & 7, idx = flat >> 3;
    if constexpr (EPI == 0) { bn = xcd * 3 + idx / 33; bm = idx % 33; }   // 792 blocks
    else                    { bn = xcd;                bm = idx;       }  // 264 blocks
  }

  const f32x4 zero = {0.f, 0.f, 0.f, 0.f};
  f32x4 acc[4][4];
#pragma unroll
  for (int i = 0; i < 4; i++)
#pragma unroll
    for (int j = 0; j < 4; j++) acc[i][j] = zero;

  const int mb = (w >> 1) << 6, nb = (w & 1) << 6;

  const int srow = (w << 5) + (lane >> 2);
  const int cseg = (lane & 3) << 3;
  const short* gA = A + (size_t)(bm * 128 + srow) * K + cseg;
  const short* gB = Bt + (size_t)(bn * 128 + srow) * K + cseg;
  const int lo0 = ((w << 5) << 6) + lane * 16;       // bytes within a buffer
  const int lo1 = lo0 + (16 << 6);

#define STAGE(buf, kb0)                                                        \
  do {                                                                         \
    ASYNC_COPY16(gA + (kb0), (char*)As[buf] + lo0);                            \
    ASYNC_COPY16(gA + (size_t)16 * K + (kb0), (char*)As[buf] + lo1);           \
    ASYNC_COPY16(gB + (kb0), (char*)Bs[buf] + lo0);                            \
    ASYNC_COPY16(gB + (size_t)16 * K + (kb0), (char*)Bs[buf] + lo1);           \
  } while (0)

  STAGE(0, 0);
  int cur = 0;
  for (int kb0 = 0; kb0 < K; kb0 += 32) {
    __syncthreads();                 // drains vmcnt -> buf[cur] ready
    if (kb0 + 32 < K) STAGE(cur ^ 1, kb0 + 32);   // prefetch flies under compute
    s16x8 af[4], bf[4];
#pragma unroll
    for (int mi = 0; mi < 4; mi++)
      af[mi] = *(const s16x8*)&As[cur][(mb + mi * 16 + l16) * 32 + quad * 8];
#pragma unroll
    for (int ni = 0; ni < 4; ni++)
      bf[ni] = *(const s16x8*)&Bs[cur][(nb + ni * 16 + l16) * 32 + quad * 8];
#pragma unroll
    for (int mi = 0; mi < 4; mi++)
#pragma unroll
      for (int ni = 0; ni < 4; ni++)
        acc[mi][ni] = __builtin_amdgcn_mfma_f32_16x16x32_bf16(af[mi], bf[ni], acc[mi][ni], 0, 0, 0);
    cur ^= 1;
  }
#undef STAGE

  if constexpr (EPI == 0) {
    const int cbase = bn * 128 + nb;          // wave-uniform
    const int which = cbase >> 10;            // 0=q 1=k 2=v
    const int hh = (cbase & 1023) >> 6;       // head, wave-uniform
#pragma unroll
    for (int mi = 0; mi < 4; mi++) {
#pragma unroll
      for (int reg = 0; reg < 4; reg++) {
        const int R = bm * 128 + mb + mi * 16 + quad * 4 + reg;
        if (R < MROWS_) {
          const int b = (R >= U_) ? 1 : 0;
          const int u = R - b * U_;
          const int t = (u - (u >> 8)) >> 8;  // u/257 for u<2056
          const int jj = u - ((t << 8) + t);
          const int bh = b * 16 + hh;
          if (which == 2) {
#pragma unroll
            for (int ni = 0; ni < 4; ni++)
              vb[((size_t)bh * UPAD_ + u) * 64 + ni * 16 + l16] = f2bf(acc[mi][ni][reg]);
          } else {
            const float *ct, *st; int pos;
            if (jj == 0) { ct = cosc; st = sinc; pos = t; }
            else         { ct = cosi; st = sini; pos = u - t - 1; }
#pragma unroll
            for (int ni = 0; ni < 4; ni++) {
              const int d = ni * 16 + l16;
              const float val = acc[mi][ni][reg];
              const float partner = __shfl_xor(val, 1, 64);  // d^1 neighbor, same row
              const float cv = ct[pos * 64 + d], sv = st[pos * 64 + d];
              float o = val * cv + ((d & 1) ? partner : -partner) * sv;
              if (which == 0) {
                o *= 0.18033688f;  // fold 1/sqrt(64) * log2(e) into q
                qb[((size_t)bh * U_ + u) * 64 + d] = f2bf(o);
              } else {
                kb[((size_t)bh * UPAD_ + u) * 64 + d] = f2bf(o);
              }
            }
          }
        }
      }
    }
  } else {
    const int cbase = bn * 128 + nb;
#pragma unroll
    for (int mi = 0; mi < 4; mi++) {
#pragma unroll
      for (int reg = 0; reg < 4; reg++) {
        const int R = bm * 128 + mb + mi * 16 + quad * 4 + reg;
        if (R < MROWS_) {
          const int b = (R >= U_) ? 1 : 0;
          const int u = R - b * U_;
          const int t = (u - (u >> 8)) >> 8;
          const int jj = u - ((t << 8) + t);
          size_t rowoff;
          if (jj) rowoff = (size_t)((b * 8 + t) * 256 + jj - 1) * 1024;
          else    rowoff = IMG_OUT_ELEMS + (size_t)(b * 8 + t) * 1024;
#pragma unroll
          for (int ni = 0; ni < 4; ni++) {
            const int Cg = cbase + ni * 16 + l16;
            outp[rowoff + Cg] = acc[mi][ni][reg] + bias[Cg];
          }
        }
      }
    }
  }
}

// ---------------- fused flash attention (img queries only) ----------------
// 1024 blocks, XCD decode (each XCD owns 4 bh -> K/V L2-resident).
// Swapped QK^T (T12): each lane owns ONE q-row (q=l16), softmax in-lane.
// Row-sum l runs on the MFMA pipe via a ones-column MFMA (l = P*1) -> lands
// directly in o_acc layout: no VALU adds, no end shuffles.
// V path: verified V^T staging (vtb from vtcam) + swizzled ds_read_b128.
__global__ __launch_bounds__(256) void attn_kernel(const short* __restrict__ q,
                                                   const short* __restrict__ k,
                                                   const short* __restrict__ vt,
                                                   short* __restrict__ x) {
  __shared__ __align__(16) short Kt[64 * 64];      // [kv][d] XOR-swizzled
  __shared__ __align__(16) short Vt[64 * 64];      // [d][kv] XOR-swizzled
  __shared__ __align__(16) short Pt[4 * 16 * 72];  // per-wave [q][kv], stride 72
  const int tid = threadIdx.x, w = tid >> 6, lane = tid & 63;
  const int l16 = lane & 15, quad = lane >> 4;
  const int flat = blockIdx.x;
  const int slot = flat >> 3;
  const int bh = ((flat & 7) << 2) + (slot >> 5);
  const int qt = slot & 31;
  const int b = bh >> 4, h = bh & 15;

  // q rows: global img row g -> fused u = g + (g>>8) + 1
  const int g = qt * 64 + w * 16 + l16;
  const int u_q = g + (g >> 8) + 1;
  const short* qp = q + ((size_t)bh * U_ + u_q) * 64;
  const s16x8 aq0 = *(const s16x8*)(qp + quad * 8);
  const s16x8 aq1 = *(const s16x8*)(qp + 32 + quad * 8);

  // reg-staging geometry: lane stages rows sr and sr+32, 16B granule c8.
  const int sr = w * 8 + (lane >> 3);              // 0..31
  const int c8 = lane & 7;
  const short* kg = k + ((size_t)bh * UPAD_ + sr) * 64 + (c8 << 3);
  const short* vg = vt + ((size_t)bh * 64 + sr) * UPAD_ + (c8 << 3);
  const int swz = ((c8 ^ (sr & 7)) << 3);          // (sr+32)&7 == sr&7
  short* const wk0 = &Kt[sr * 64 + swz];
  short* const wk1 = &Kt[(sr + 32) * 64 + swz];
  short* const wv0 = &Vt[sr * 64 + swz];
  short* const wv1 = &Vt[(sr + 32) * 64 + swz];

  // swizzled LDS read columns (shorts); row = ni*16+l16 -> row&7 = l16&7
  const int cK0 = (quad * 8) ^ ((l16 & 7) << 3);
  const int cK1 = (32 + quad * 8) ^ ((l16 & 7) << 3);
  short* const pw = Pt + (w * 16 + l16) * 72;

  const f32x4 zero = {0.f, 0.f, 0.f, 0.f};
  const s16x8 vones = {16256, 16256, 16256, 16256, 16256, 16256, 16256, 16256}; // bf16 1.0
  float m_r = -3e38f;
  f32x4 l_acc = zero;
  f32x4 o_acc[4];
#pragma unroll
  for (int r = 0; r < 4; r++) o_acc[r] = zero;

  // prologue: stage tile 0 into regs
  s16x8 rk0 = *(const s16x8*)(kg);
  s16x8 rk1 = *(const s16x8*)(kg + 2048);
  s16x8 rv0 = *(const s16x8*)(vg);
  s16x8 rv1 = *(const s16x8*)(vg + 32 * UPAD_);
  kg += 64 * 64;
  vg += 64;

  for (int kv0 = 0; kv0 < U_; kv0 += 64) {
    __syncthreads();                 // prev tile's LDS reads complete
    *(s16x8*)wk0 = rk0;
    *(s16x8*)wk1 = rk1;
    *(s16x8*)wv0 = rv0;
    *(s16x8*)wv1 = rv1;
    __syncthreads();                 // LDS ready
    if (kv0 + 64 < U_) {             // issue next-tile loads; hide under compute
      rk0 = *(const s16x8*)(kg);
      rk1 = *(const s16x8*)(kg + 2048);
      rv0 = *(const s16x8*)(vg);
      rv1 = *(const s16x8*)(vg + 32 * UPAD_);
      kg += 64 * 64;
      vg += 64;
    }

    // S^T = K Q^T: C row = kv (ni*16+quad*4+reg), col = q = l16
    f32x4 sT[4];
    __builtin_amdgcn_s_setprio(1);
#pragma unroll
    for (int ni = 0; ni < 4; ni++) {
      const s16x8 b0 = *(const s16x8*)&Kt[(ni * 16 + l16) * 64 + cK0];
      const s16x8 b1 = *(const s16x8*)&Kt[(ni * 16 + l16) * 64 + cK1];
      f32x4 z = __builtin_amdgcn_mfma_f32_16x16x32_bf16(b0, aq0, zero, 0, 0, 0);
      sT[ni] = __builtin_amdgcn_mfma_f32_16x16x32_bf16(b1, aq1, z, 0, 0, 0);
    }
    __builtin_amdgcn_s_setprio(0);

    // tail tile: real kv are 2048..2055 -> kv_local = ni*16+quad*4+reg < 8
    if (kv0 == 2048) {
#pragma unroll
      for (int ni = 0; ni < 4; ni++) {
        if (ni > 0 || quad >= 2) {
          sT[ni][0] = -1e30f; sT[ni][1] = -1e30f;
          sT[ni][2] = -1e30f; sT[ni][3] = -1e30f;
        }
      }
    }

    // in-lane row max (v_max3 tree) + 2 cross-lane ops
    float t0 = fmaxf(fmaxf(sT[0][0], sT[0][1]), sT[0][2]);
    float t1 = fmaxf(fmaxf(sT[0][3], sT[1][0]), sT[1][1]);
    float t2 = fmaxf(fmaxf(sT[1][2], sT[1][3]), sT[2][0]);
    float t3 = fmaxf(fmaxf(sT[2][1], sT[2][2]), sT[2][3]);
    float t4 = fmaxf(fmaxf(sT[3][0], sT[3][1]), sT[3][2]);
    float mx = fmaxf(fmaxf(fmaxf(t0, t1), t2), fmaxf(fmaxf(t3, t4), sT[3][3]));
    mx = fmaxf(mx, __shfl_xor(mx, 16, 64));
    mx = fmaxf(mx, __shfl_xor(mx, 32, 64));

    // T13 defer-max: rescale only when max grew by >= 8 (exp2 domain)
    if (__any(mx > m_r + 8.f)) {
      const float mnew = fmaxf(m_r, mx);
      const float al = exp2a(m_r - mnew);
      m_r = mnew;
      float aR[4];
#pragma unroll
      for (int reg = 0; reg < 4; reg++) aR[reg] = __shfl(al, quad * 4 + reg, 64);
#pragma unroll
      for (int ni = 0; ni < 4; ni++)
#pragma unroll
        for (int reg = 0; reg < 4; reg++) o_acc[ni][reg] *= aR[reg];
#pragma unroll
      for (int reg = 0; reg < 4; reg++) l_acc[reg] *= aR[reg];
    }

#pragma unroll
    for (int ni = 0; ni < 4; ni++)
#pragma unroll
      for (int reg = 0; reg < 4; reg++)
        sT[ni][reg] = exp2a(sT[ni][reg] - m_r);

    // P -> Pt[q=l16][kv]: one b64 per ni
#pragma unroll
    for (int ni = 0; ni < 4; ni++) {
      uint2 pk;
      pk.x = cvt_pk_bf16(sT[ni][0], sT[ni][1]);
      pk.y = cvt_pk_bf16(sT[ni][2], sT[ni][3]);
      *(uint2*)&pw[ni * 16 + quad * 4] = pk;
    }

    // O += P V ;  l += P * 1  (row-sum on the MFMA pipe)
    const s16x8 ap0 = *(const s16x8*)&pw[quad * 8];
    const s16x8 ap1 = *(const s16x8*)&pw[32 + quad * 8];
    __builtin_amdgcn_s_setprio(1);
    l_acc = __builtin_amdgcn_mfma_f32_16x16x32_bf16(ap0, vones, l_acc, 0, 0, 0);
#pragma unroll
    for (int ni = 0; ni < 4; ni++) {
      const s16x8 bv = *(const s16x8*)&Vt[(ni * 16 + l16) * 64 + cK0];
      o_acc[ni] = __builtin_amdgcn_mfma_f32_16x16x32_bf16(ap0, bv, o_acc[ni], 0, 0, 0);
    }
    l_acc = __builtin_amdgcn_mfma_f32_16x16x32_bf16(ap1, vones, l_acc, 0, 0, 0);
#pragma unroll
    for (int ni = 0; ni < 4; ni++) {
      const s16x8 bv = *(const s16x8*)&Vt[(ni * 16 + l16) * 64 + cK1];
      o_acc[ni] = __builtin_amdgcn_mfma_f32_16x16x32_bf16(ap1, bv, o_acc[ni], 0, 0, 0);
    }
    __builtin_amdgcn_s_setprio(0);
  }

  // l_acc already in o_acc layout (row = quad*4+reg); all 16 cols identical
  f32x4 linv;
#pragma unroll
  for (int reg = 0; reg < 4; reg++) linv[reg] = 1.f / l_acc[reg];

  // write x[b*2056+u][h*64+d] bf16 (o row = quad*4+reg, col = ni*16+l16)
#pragma unroll
  for (int reg = 0; reg < 4; reg++) {
    const int go = qt * 64 + w * 16 + quad * 4 + reg;
    const int u_o = go + (go >> 8) + 1;
#pragma unroll
    for (int ni = 0; ni < 4; ni++)
      x[((size_t)(b * U_ + u_o)) * 1024 + h * 64 + ni * 16 + l16] =
          f2bf(o_acc[ni][reg] * linv[reg]);
  }
}

// ---------------- fused vt transpose + cam-query attention ----------------
// blocks 0..1055: bf16 v[bh][2112][64] -> vt[bh][64][2112] (zero pad rows)
// blocks 1056..1311: cam attention; decode puts all 8 t-blocks of a bh on the
// SAME XCD (block_id%8 == bh&7) so K/V re-reads hit that XCD's L2.
__global__ __launch_bounds__(256) void vtcam_kernel(const short* __restrict__ v,
                                                    short* __restrict__ vt,
                                                    const short* __restrict__ q,
                                                    const short* __restrict__ k,
                                                    short* __restrict__ x) {
  __shared__ __align__(16) char smem[16448];
  const int bid = blockIdx.x;
  const int tid = threadIdx.x;
  if (bid < 1056) {
    short (*t2)[65] = (short(*)[65])smem;          // 64*65*2 = 8320 B
    int kt = bid % 33, bh = bid / 33;
#pragma unroll
    for (int i = 0; i < 16; i++) {
      int e = tid + i * 256; int r = e >> 6, c = e & 63;
      short vv = v[((size_t)bh * UPAD_ + kt * 64 + r) * 64 + c];
      t2[r][c] = (kt * 64 + r < U_) ? vv : (short)0;
    }
    __syncthreads();
#pragma unroll
    for (int i = 0; i < 16; i++) {
      int e = tid + i * 256; int d = e >> 6, c = e & 63;
      vt[((size_t)bh * 64 + d) * UPAD_ + kt * 64 + c] = t2[c][d];
    }
    return;
  }
  float* sb = (float*)smem;                        // 2056 floats
  float* red = sb + U_;                            // 8 floats
  float (*obuf)[64] = (float(*)[64])(red + 8);     // 32*64 floats
  const int i0 = bid - 1056;                       // XCD of this block = i0 & 7
  const int bh = (i0 & 7) + ((i0 >> 6) << 3);      // bh&7 == i0&7 -> same XCD per bh
  const int t = (i0 >> 3) & 7;
  const int b = bh >> 4, h = bh & 15;
  const int L = (t + 1) * 257;
  const int lane = tid & 63, w = tid >> 6;
  const int u_q = t * 257;

  float qf[64];
  {
    const short* qpp = q + ((size_t)bh * U_ + u_q) * 64;
#pragma unroll
    for (int i = 0; i < 8; i++) {
      const s16x8 qv = *(const s16x8*)(qpp + i * 8);
#pragma unroll
      for (int j = 0; j < 8; j++) qf[i * 8 + j] = b2f(qv[j]);
    }
  }

  float lm = -3e38f;
  for (int kv = tid; kv < L; kv += 256) {
    const short* kp = k + ((size_t)bh * UPAD_ + kv) * 64;
    float s = 0.f;
#pragma unroll
    for (int i = 0; i < 8; i++) {
      const s16x8 kvv = *(const s16x8*)(kp + i * 8);
#pragma unroll
      for (int j = 0; j < 8; j++) s += qf[i * 8 + j] * b2f(kvv[j]);
    }
    sb[kv] = s;
    lm = fmaxf(lm, s);
  }
#pragma unroll
  for (int d = 1; d < 64; d <<= 1) lm = fmaxf(lm, __shfl_xor(lm, d, 64));
  if (lane == 0) red[w] = lm;
  __syncthreads();
  const float m = fmaxf(fmaxf(red[0], red[1]), fmaxf(red[2], red[3]));

  float ls = 0.f;
  for (int kv = tid; kv < L; kv += 256) {
    const float p = exp2a(sb[kv] - m);
    sb[kv] = p;
    ls += p;
  }
#pragma unroll
  for (int d = 1; d < 64; d <<= 1) ls += __shfl_xor(ls, d, 64);
  if (lane == 0) red[4 + w] = ls;
  __syncthreads();
  const float linv = 1.f / (red[4] + red[5] + red[6] + red[7]);

  const int d0 = (tid & 7) << 3;
  const int slot = tid >> 3;
  float acc[8];
#pragma unroll
  for (int j = 0; j < 8; j++) acc[j] = 0.f;
  for (int kv = slot; kv < L; kv += 32) {
    const float p = sb[kv];
    const s16x8 vv = *(const s16x8*)(v + ((size_t)bh * UPAD_ + kv) * 64 + d0);
#pragma unroll
    for (int j = 0; j < 8; j++) acc[j] += p * b2f(vv[j]);
  }
#pragma unroll
  for (int j = 0; j < 8; j++) obuf[slot][d0 + j] = acc[j];
  __syncthreads();
  if (tid < 64) {
    float s = 0.f;
#pragma unroll
    for (int i = 0; i < 32; i++) s += obuf[i][tid];
    x[((size_t)(b * U_ + u_q)) * 1024 + h * 64 + tid] = f2bf(s * linv);
  }
}

// ---------------- launch ----------------
extern "C" void kernel_launch(void* const* d_in, const int* in_sizes, int n_in,
                              void* d_out, int out_size, void* d_ws, size_t ws_size,
                              hipStream_t stream) {
  const float* img   = (const float*)d_in[0];
  const float* cam   = (const float*)d_in[1];
  const float* wqkv  = (const float*)d_in[2];
  const float* wproj = (const float*)d_in[3];
  const float* bias  = (const float*)d_in[4];
  const float* cosi  = (const float*)d_in[5];
  const float* sini  = (const float*)d_in[6];
  const float* cosc  = (const float*)d_in[7];
  const float* sinc  = (const float*)d_in[8];
  float* outp = (float*)d_out;

  char* ws = (char*)d_ws;
  short* Xb     = (short*)(ws + OFF_XB);
  short* Wqkvt  = (short*)(ws + OFF_WQKVT);
  short* Wprojt = (short*)(ws + OFF_WPROJT);
  short* qb     = (short*)(ws + OFF_Q);
  short* kb     = (short*)(ws + OFF_K);
  short* vb     = (short*)(ws + OFF_V);
  short* vtb    = (short*)(ws + OFF_VT);
  short* xb     = (short*)(ws + OFF_X);

  prep_kernel<<<8208, 256, 0, stream>>>(img, cam, Xb, wqkv, Wqkvt, wproj, Wprojt);
  gemm_kernel<0><<<792, 256, 0, stream>>>(Xb, Wqkvt, cosi, sini, cosc, sinc,
                                          qb, kb, vb, nullptr, nullptr);
  vtcam_kernel<<<1312, 256, 0, stream>>>(vb, vtb, qb, kb, xb);
  attn_kernel<<<1024, 256, 0, stream>>>(qb, kb, vtb, xb);
  gemm_kernel<1><<<264, 256, 0, stream>>>(xb, Wprojt, nullptr, nullptr, nullptr, nullptr,
                                          nullptr, nullptr, nullptr, bias, outp);
}

// Round 8
// 271.056 us; speedup vs baseline: 1.3911x; 1.0056x over previous
//
#include <hip/hip_runtime.h>

// ---------------- problem constants ----------------
#define T_ 8
#define N_ 256
#define C_ 1024
#define H_ 16
#define D_ 64
#define U_ 2056      // fused tokens per batch = T*(N+1)
#define UPAD_ 2112   // 33*64
#define MROWS_ 4112  // B*U
#define MPAD_ 4224   // 33*128
#define IMG_OUT_ELEMS 4194304  // 2*8*256*1024

typedef __attribute__((ext_vector_type(4))) float f32x4;
typedef __attribute__((ext_vector_type(8))) short s16x8;
typedef __attribute__((ext_vector_type(4))) short s16x4;

__device__ __forceinline__ short f2bf(float f) {
  union { float f; unsigned u; } a; a.f = f;
  unsigned u = a.u;
  return (short)((u + 0x7fffu + ((u >> 16) & 1u)) >> 16);
}

__device__ __forceinline__ float b2f(short s) {
  union { unsigned u; float f; } a;
  a.u = ((unsigned)(unsigned short)s) << 16;
  return a.f;
}

// bare v_exp_f32 (2^x). q is pre-scaled by log2(e) so softmax runs in exp2 domain.
__device__ __forceinline__ float exp2a(float x) {
  float r; asm("v_exp_f32 %0, %1" : "=v"(r) : "v"(x)); return r;
}

__device__ __forceinline__ unsigned cvt_pk_bf16(float lo, float hi) {
  unsigned r; asm("v_cvt_pk_bf16_f32 %0, %1, %2" : "=v"(r) : "v"(lo), "v"(hi)); return r;
}

#define ASYNC_COPY16(gp, lp)                                                   \
  __builtin_amdgcn_global_load_lds((const __attribute__((address_space(1))) void*)(gp), \
                                   (__attribute__((address_space(3))) void*)(lp), 16, 0, 0)

// ---------------- workspace offsets (bytes) ----------------
constexpr size_t OFF_XB     = 0;                         // 4224*1024*2
constexpr size_t OFF_WQKVT  = OFF_XB + 8650752;          // 3072*1024*2
constexpr size_t OFF_WPROJT = OFF_WQKVT + 6291456;       // 1024*1024*2
constexpr size_t OFF_Q      = OFF_WPROJT + 2097152;      // 32*2056*64*2
constexpr size_t OFF_K      = OFF_Q + 8421376;           // 32*2112*64*2
constexpr size_t OFF_V      = OFF_K + 8650752;           // 32*2112*64*2
constexpr size_t OFF_VT     = OFF_V + 8650752;           // 32*64*2112*2
constexpr size_t OFF_X      = OFF_VT + 8650752;          // 4224*1024*2
// total ~60 MB

// ---------------- fused prep: pack X + both weight transposes ----------------
__global__ __launch_bounds__(256) void prep_kernel(const float* __restrict__ img,
                                                   const float* __restrict__ cam,
                                                   short* __restrict__ Xb,
                                                   const float* __restrict__ wqkv,
                                                   short* __restrict__ Wqkvt,
                                                   const float* __restrict__ wproj,
                                                   short* __restrict__ Wprojt) {
  __shared__ float tile[32][33];
  const int bid = blockIdx.x;
  if (bid < 4112) {
    int gt = bid * 256 + threadIdx.x;
    int e = gt << 2;                      // 4 floats per thread, exact cover of 4112*1024
    int row = e >> 10, col = e & 1023;
    int b = row / U_, u = row % U_, t = u / 257, jj = u % 257;
    const float* src = jj ? (img + ((size_t)((b * 8 + t) * 256 + (jj - 1)) << 10))
                          : (cam + ((size_t)(b * 8 + t) << 10));
    float4 f = *(const float4*)(src + col);
    s16x4 o;
    o[0] = f2bf(f.x); o[1] = f2bf(f.y); o[2] = f2bf(f.z); o[3] = f2bf(f.w);
    *(s16x4*)(Xb + ((size_t)row << 10) + col) = o;
    return;
  }
  const float* in; short* out; int Cc, bx, by;
  if (bid < 4112 + 3072) {
    int i = bid - 4112; bx = i % 96; by = i / 96; in = wqkv; out = Wqkvt; Cc = 3072;
  } else {
    int i = bid - 7184; bx = i % 32; by = i / 32; in = wproj; out = Wprojt; Cc = 1024;
  }
  constexpr int R = 1024;
  int tx = threadIdx.x & 31, ty = threadIdx.x >> 5;
  int col0 = bx << 5, row0 = by << 5;
#pragma unroll
  for (int i = 0; i < 4; i++) {
    int r = ty + i * 8;
    tile[r][tx] = in[(size_t)(row0 + r) * Cc + col0 + tx];
  }
  __syncthreads();
#pragma unroll
  for (int i = 0; i < 4; i++) {
    int r = ty + i * 8;
    out[(size_t)(col0 + r) * R + row0 + tx] = f2bf(tile[tx][r]);
  }
}

// ---------------- 64x128 bf16 GEMM, Bt is [N][K] row-major ----------------
// BM=64 retile: gemm<0> 66x24=1584 blocks (6.2/CU), gemm<1> 66x8=528 (2.1/CU)
// -- removes the 1-block/CU (EPI1) and 29%-tail (EPI0) grid pathologies.
// Double-buffered LDS; prefetch-after-barrier (T3 minimum 2-phase).
// EPI 0: QKV+RoPE.  EPI 1: proj+bias.
template <int EPI>
__global__ __launch_bounds__(256) void gemm_kernel(
    const short* __restrict__ A, const short* __restrict__ Bt,
    const float* __restrict__ cosi, const float* __restrict__ sini,
    const float* __restrict__ cosc, const float* __restrict__ sinc,
    short* __restrict__ qb, short* __restrict__ kb, short* __restrict__ vb,
    const float* __restrict__ bias, float* __restrict__ outp) {
  constexpr int K = 1024;
  __shared__ __align__(16) short As[2][64 * 32];
  __shared__ __align__(16) short Bs[2][128 * 32];
  const int tid = threadIdx.x, w = tid >> 6, lane = tid & 63;
  const int l16 = lane & 15, quad = lane >> 4;

  int bn, bm;
  {
    const int flat = blockIdx.x;
    const int xcd = flat & 7, idx = flat >> 3;
    if constexpr (EPI == 0) { bn = xcd * 3 + idx / 66; bm = idx % 66; }   // 1584 blocks
    else                    { bn = xcd;                bm = idx;       }  // 528 blocks
  }

  const f32x4 zero = {0.f, 0.f, 0.f, 0.f};
  f32x4 acc[2][4];
#pragma unroll
  for (int i = 0; i < 2; i++)
#pragma unroll
    for (int j = 0; j < 4; j++) acc[i][j] = zero;

  const int mb = (w >> 1) << 5, nb = (w & 1) << 6;   // wave tile 32x64

  // staging: A 64x32 = 1 copy/thread; B 128x32 = 2 copies/thread
  const int srow = tid >> 2;                 // 0..63
  const int cseg = (tid & 3) << 3;
  const short* gA = A + (size_t)(bm * 64 + srow) * K + cseg;
  const short* gB = Bt + (size_t)(bn * 128 + srow) * K + cseg;
  const int lo = tid * 16;                   // bytes

#define STAGE(buf, kb0)                                                        \
  do {                                                                         \
    ASYNC_COPY16(gA + (kb0), (char*)As[buf] + lo);                             \
    ASYNC_COPY16(gB + (kb0), (char*)Bs[buf] + lo);                             \
    ASYNC_COPY16(gB + (size_t)64 * K + (kb0), (char*)Bs[buf] + lo + 4096);     \
  } while (0)

  STAGE(0, 0);
  int cur = 0;
  for (int kb0 = 0; kb0 < K; kb0 += 32) {
    __syncthreads();                 // drains vmcnt -> buf[cur] ready
    if (kb0 + 32 < K) STAGE(cur ^ 1, kb0 + 32);   // prefetch flies under compute
    s16x8 af[2], bf[4];
#pragma unroll
    for (int mi = 0; mi < 2; mi++)
      af[mi] = *(const s16x8*)&As[cur][(mb + mi * 16 + l16) * 32 + quad * 8];
#pragma unroll
    for (int ni = 0; ni < 4; ni++)
      bf[ni] = *(const s16x8*)&Bs[cur][(nb + ni * 16 + l16) * 32 + quad * 8];
#pragma unroll
    for (int mi = 0; mi < 2; mi++)
#pragma unroll
      for (int ni = 0; ni < 4; ni++)
        acc[mi][ni] = __builtin_amdgcn_mfma_f32_16x16x32_bf16(af[mi], bf[ni], acc[mi][ni], 0, 0, 0);
    cur ^= 1;
  }
#undef STAGE

  if constexpr (EPI == 0) {
    const int cbase = bn * 128 + nb;          // wave-uniform
    const int which = cbase >> 10;            // 0=q 1=k 2=v
    const int hh = (cbase & 1023) >> 6;       // head, wave-uniform
#pragma unroll
    for (int mi = 0; mi < 2; mi++) {
#pragma unroll
      for (int reg = 0; reg < 4; reg++) {
        const int R = bm * 64 + mb + mi * 16 + quad * 4 + reg;
        if (R < MROWS_) {
          const int b = (R >= U_) ? 1 : 0;
          const int u = R - b * U_;
          const int t = (u - (u >> 8)) >> 8;  // u/257 for u<2056
          const int jj = u - ((t << 8) + t);
          const int bh = b * 16 + hh;
          if (which == 2) {
#pragma unroll
            for (int ni = 0; ni < 4; ni++)
              vb[((size_t)bh * UPAD_ + u) * 64 + ni * 16 + l16] = f2bf(acc[mi][ni][reg]);
          } else {
            const float *ct, *st; int pos;
            if (jj == 0) { ct = cosc; st = sinc; pos = t; }
            else         { ct = cosi; st = sini; pos = u - t - 1; }
#pragma unroll
            for (int ni = 0; ni < 4; ni++) {
              const int d = ni * 16 + l16;
              const float val = acc[mi][ni][reg];
              const float partner = __shfl_xor(val, 1, 64);  // d^1 neighbor, same row
              const float cv = ct[pos * 64 + d], sv = st[pos * 64 + d];
              float o = val * cv + ((d & 1) ? partner : -partner) * sv;
              if (which == 0) {
                o *= 0.18033688f;  // fold 1/sqrt(64) * log2(e) into q
                qb[((size_t)bh * U_ + u) * 64 + d] = f2bf(o);
              } else {
                kb[((size_t)bh * UPAD_ + u) * 64 + d] = f2bf(o);
              }
            }
          }
        }
      }
    }
  } else {
    const int cbase = bn * 128 + nb;
#pragma unroll
    for (int mi = 0; mi < 2; mi++) {
#pragma unroll
      for (int reg = 0; reg < 4; reg++) {
        const int R = bm * 64 + mb + mi * 16 + quad * 4 + reg;
        if (R < MROWS_) {
          const int b = (R >= U_) ? 1 : 0;
          const int u = R - b * U_;
          const int t = (u - (u >> 8)) >> 8;
          const int jj = u - ((t << 8) + t);
          size_t rowoff;
          if (jj) rowoff = (size_t)((b * 8 + t) * 256 + jj - 1) * 1024;
          else    rowoff = IMG_OUT_ELEMS + (size_t)(b * 8 + t) * 1024;
#pragma unroll
          for (int ni = 0; ni < 4; ni++) {
            const int Cg = cbase + ni * 16 + l16;
            outp[rowoff + Cg] = acc[mi][ni][reg] + bias[Cg];
          }
        }
      }
    }
  }
}

// ---------------- fused flash attention (img queries only) ----------------
// 1024 blocks, XCD decode (each XCD owns 4 bh -> K/V L2-resident).
// Swapped QK^T (T12): each lane owns ONE q-row (q=l16), softmax in-lane.
// Row-sum l runs on the MFMA pipe via a ones-column MFMA (l = P*1).
// V path: verified V^T staging (vtb from vtcam) + swizzled ds_read_b128.
__global__ __launch_bounds__(256) void attn_kernel(const short* __restrict__ q,
                                                   const short* __restrict__ k,
                                                   const short* __restrict__ vt,
                                                   short* __restrict__ x) {
  __shared__ __align__(16) short Kt[64 * 64];      // [kv][d] XOR-swizzled
  __shared__ __align__(16) short Vt[64 * 64];      // [d][kv] XOR-swizzled
  __shared__ __align__(16) short Pt[4 * 16 * 72];  // per-wave [q][kv], stride 72
  const int tid = threadIdx.x, w = tid >> 6, lane = tid & 63;
  const int l16 = lane & 15, quad = lane >> 4;
  const int flat = blockIdx.x;
  const int slot = flat >> 3;
  const int bh = ((flat & 7) << 2) + (slot >> 5);
  const int qt = slot & 31;
  const int b = bh >> 4, h = bh & 15;

  // q rows: global img row g -> fused u = g + (g>>8) + 1
  const int g = qt * 64 + w * 16 + l16;
  const int u_q = g + (g >> 8) + 1;
  const short* qp = q + ((size_t)bh * U_ + u_q) * 64;
  const s16x8 aq0 = *(const s16x8*)(qp + quad * 8);
  const s16x8 aq1 = *(const s16x8*)(qp + 32 + quad * 8);

  // reg-staging geometry: lane stages rows sr and sr+32, 16B granule c8.
  const int sr = w * 8 + (lane >> 3);              // 0..31
  const int c8 = lane & 7;
  const short* kg = k + ((size_t)bh * UPAD_ + sr) * 64 + (c8 << 3);
  const short* vg = vt + ((size_t)bh * 64 + sr) * UPAD_ + (c8 << 3);
  const int swz = ((c8 ^ (sr & 7)) << 3);          // (sr+32)&7 == sr&7
  short* const wk0 = &Kt[sr * 64 + swz];
  short* const wk1 = &Kt[(sr + 32) * 64 + swz];
  short* const wv0 = &Vt[sr * 64 + swz];
  short* const wv1 = &Vt[(sr + 32) * 64 + swz];

  // swizzled LDS read columns (shorts); row = ni*16+l16 -> row&7 = l16&7
  const int cK0 = (quad * 8) ^ ((l16 & 7) << 3);
  const int cK1 = (32 + quad * 8) ^ ((l16 & 7) << 3);
  short* const pw = Pt + (w * 16 + l16) * 72;

  const f32x4 zero = {0.f, 0.f, 0.f, 0.f};
  const s16x8 vones = {16256, 16256, 16256, 16256, 16256, 16256, 16256, 16256}; // bf16 1.0
  float m_r = -3e38f;
  f32x4 l_acc = zero;
  f32x4 o_acc[4];
#pragma unroll
  for (int r = 0; r < 4; r++) o_acc[r] = zero;

  // prologue: stage tile 0 into regs
  s16x8 rk0 = *(const s16x8*)(kg);
  s16x8 rk1 = *(const s16x8*)(kg + 2048);
  s16x8 rv0 = *(const s16x8*)(vg);
  s16x8 rv1 = *(const s16x8*)(vg + 32 * UPAD_);
  kg += 64 * 64;
  vg += 64;

  for (int kv0 = 0; kv0 < U_; kv0 += 64) {
    __syncthreads();                 // prev tile's LDS reads complete
    *(s16x8*)wk0 = rk0;
    *(s16x8*)wk1 = rk1;
    *(s16x8*)wv0 = rv0;
    *(s16x8*)wv1 = rv1;
    __syncthreads();                 // LDS ready
    if (kv0 + 64 < U_) {             // issue next-tile loads; hide under compute
      rk0 = *(const s16x8*)(kg);
      rk1 = *(const s16x8*)(kg + 2048);
      rv0 = *(const s16x8*)(vg);
      rv1 = *(const s16x8*)(vg + 32 * UPAD_);
      kg += 64 * 64;
      vg += 64;
    }

    // S^T = K Q^T: C row = kv (ni*16+quad*4+reg), col = q = l16
    f32x4 sT[4];
    __builtin_amdgcn_s_setprio(1);
#pragma unroll
    for (int ni = 0; ni < 4; ni++) {
      const s16x8 b0 = *(const s16x8*)&Kt[(ni * 16 + l16) * 64 + cK0];
      const s16x8 b1 = *(const s16x8*)&Kt[(ni * 16 + l16) * 64 + cK1];
      f32x4 z = __builtin_amdgcn_mfma_f32_16x16x32_bf16(b0, aq0, zero, 0, 0, 0);
      sT[ni] = __builtin_amdgcn_mfma_f32_16x16x32_bf16(b1, aq1, z, 0, 0, 0);
    }
    __builtin_amdgcn_s_setprio(0);

    // tail tile: real kv are 2048..2055 -> kv_local = ni*16+quad*4+reg < 8
    if (kv0 == 2048) {
#pragma unroll
      for (int ni = 0; ni < 4; ni++) {
        if (ni > 0 || quad >= 2) {
          sT[ni][0] = -1e30f; sT[ni][1] = -1e30f;
          sT[ni][2] = -1e30f; sT[ni][3] = -1e30f;
        }
      }
    }

    // in-lane row max (v_max3 tree) + 2 cross-lane ops
    float t0 = fmaxf(fmaxf(sT[0][0], sT[0][1]), sT[0][2]);
    float t1 = fmaxf(fmaxf(sT[0][3], sT[1][0]), sT[1][1]);
    float t2 = fmaxf(fmaxf(sT[1][2], sT[1][3]), sT[2][0]);
    float t3 = fmaxf(fmaxf(sT[2][1], sT[2][2]), sT[2][3]);
    float t4 = fmaxf(fmaxf(sT[3][0], sT[3][1]), sT[3][2]);
    float mx = fmaxf(fmaxf(fmaxf(t0, t1), t2), fmaxf(fmaxf(t3, t4), sT[3][3]));
    mx = fmaxf(mx, __shfl_xor(mx, 16, 64));
    mx = fmaxf(mx, __shfl_xor(mx, 32, 64));

    // T13 defer-max: rescale only when max grew by >= 8 (exp2 domain)
    if (__any(mx > m_r + 8.f)) {
      const float mnew = fmaxf(m_r, mx);
      const float al = exp2a(m_r - mnew);
      m_r = mnew;
      float aR[4];
#pragma unroll
      for (int reg = 0; reg < 4; reg++) aR[reg] = __shfl(al, quad * 4 + reg, 64);
#pragma unroll
      for (int ni = 0; ni < 4; ni++)
#pragma unroll
        for (int reg = 0; reg < 4; reg++) o_acc[ni][reg] *= aR[reg];
#pragma unroll
      for (int reg = 0; reg < 4; reg++) l_acc[reg] *= aR[reg];
    }

#pragma unroll
    for (int ni = 0; ni < 4; ni++)
#pragma unroll
      for (int reg = 0; reg < 4; reg++)
        sT[ni][reg] = exp2a(sT[ni][reg] - m_r);

    // P -> Pt[q=l16][kv]: one b64 per ni
#pragma unroll
    for (int ni = 0; ni < 4; ni++) {
      uint2 pk;
      pk.x = cvt_pk_bf16(sT[ni][0], sT[ni][1]);
      pk.y = cvt_pk_bf16(sT[ni][2], sT[ni][3]);
      *(uint2*)&pw[ni * 16 + quad * 4] = pk;
    }

    // O += P V ;  l += P * 1  (row-sum on the MFMA pipe)
    const s16x8 ap0 = *(const s16x8*)&pw[quad * 8];
    const s16x8 ap1 = *(const s16x8*)&pw[32 + quad * 8];
    __builtin_amdgcn_s_setprio(1);
    l_acc = __builtin_amdgcn_mfma_f32_16x16x32_bf16(ap0, vones, l_acc, 0, 0, 0);
#pragma unroll
    for (int ni = 0; ni < 4; ni++) {
      const s16x8 bv = *(const s16x8*)&Vt[(ni * 16 + l16) * 64 + cK0];
      o_acc[ni] = __builtin_amdgcn_mfma_f32_16x16x32_bf16(ap0, bv, o_acc[ni], 0, 0, 0);
    }
    l_acc = __builtin_amdgcn_mfma_f32_16x16x32_bf16(ap1, vones, l_acc, 0, 0, 0);
#pragma unroll
    for (int ni = 0; ni < 4; ni++) {
      const s16x8 bv = *(const s16x8*)&Vt[(ni * 16 + l16) * 64 + cK1];
      o_acc[ni] = __builtin_amdgcn_mfma_f32_16x16x32_bf16(ap1, bv, o_acc[ni], 0, 0, 0);
    }
    __builtin_amdgcn_s_setprio(0);
  }

  // l_acc already in o_acc layout (row = quad*4+reg); all 16 cols identical
  f32x4 linv;
#pragma unroll
  for (int reg = 0; reg < 4; reg++) linv[reg] = 1.f / l_acc[reg];

  // write x[b*2056+u][h*64+d] bf16 (o row = quad*4+reg, col = ni*16+l16)
#pragma unroll
  for (int reg = 0; reg < 4; reg++) {
    const int go = qt * 64 + w * 16 + quad * 4 + reg;
    const int u_o = go + (go >> 8) + 1;
#pragma unroll
    for (int ni = 0; ni < 4; ni++)
      x[((size_t)(b * U_ + u_o)) * 1024 + h * 64 + ni * 16 + l16] =
          f2bf(o_acc[ni][reg] * linv[reg]);
  }
}

// ---------------- fused vt transpose + cam-query attention ----------------
// blocks 0..1055: bf16 v[bh][2112][64] -> vt[bh][64][2112] (zero pad rows)
// blocks 1056..1311: cam attention; decode puts all 8 t-blocks of a bh on the
// SAME XCD (block_id%8 == bh&7) so K/V re-reads hit that XCD's L2.
__global__ __launch_bounds__(256) void vtcam_kernel(const short* __restrict__ v,
                                                    short* __restrict__ vt,
                                                    const short* __restrict__ q,
                                                    const short* __restrict__ k,
                                                    short* __restrict__ x) {
  __shared__ __align__(16) char smem[16448];
  const int bid = blockIdx.x;
  const int tid = threadIdx.x;
  if (bid < 1056) {
    short (*t2)[65] = (short(*)[65])smem;          // 64*65*2 = 8320 B
    int kt = bid % 33, bh = bid / 33;
#pragma unroll
    for (int i = 0; i < 16; i++) {
      int e = tid + i * 256; int r = e >> 6, c = e & 63;
      short vv = v[((size_t)bh * UPAD_ + kt * 64 + r) * 64 + c];
      t2[r][c] = (kt * 64 + r < U_) ? vv : (short)0;
    }
    __syncthreads();
#pragma unroll
    for (int i = 0; i < 16; i++) {
      int e = tid + i * 256; int d = e >> 6, c = e & 63;
      vt[((size_t)bh * 64 + d) * UPAD_ + kt * 64 + c] = t2[c][d];
    }
    return;
  }
  float* sb = (float*)smem;                        // 2056 floats
  float* red = sb + U_;                            // 8 floats
  float (*obuf)[64] = (float(*)[64])(red + 8);     // 32*64 floats
  const int i0 = bid - 1056;                       // XCD of this block = i0 & 7
  const int bh = (i0 & 7) + ((i0 >> 6) << 3);      // bh&7 == i0&7 -> same XCD per bh
  const int t = (i0 >> 3) & 7;
  const int b = bh >> 4, h = bh & 15;
  const int L = (t + 1) * 257;
  const int lane = tid & 63, w = tid >> 6;
  const int u_q = t * 257;

  float qf[64];
  {
    const short* qpp = q + ((size_t)bh * U_ + u_q) * 64;
#pragma unroll
    for (int i = 0; i < 8; i++) {
      const s16x8 qv = *(const s16x8*)(qpp + i * 8);
#pragma unroll
      for (int j = 0; j < 8; j++) qf[i * 8 + j] = b2f(qv[j]);
    }
  }

  float lm = -3e38f;
  for (int kv = tid; kv < L; kv += 256) {
    const short* kp = k + ((size_t)bh * UPAD_ + kv) * 64;
    float s = 0.f;
#pragma unroll
    for (int i = 0; i < 8; i++) {
      const s16x8 kvv = *(const s16x8*)(kp + i * 8);
#pragma unroll
      for (int j = 0; j < 8; j++) s += qf[i * 8 + j] * b2f(kvv[j]);
    }
    sb[kv] = s;
    lm = fmaxf(lm, s);
  }
#pragma unroll
  for (int d = 1; d < 64; d <<= 1) lm = fmaxf(lm, __shfl_xor(lm, d, 64));
  if (lane == 0) red[w] = lm;
  __syncthreads();
  const float m = fmaxf(fmaxf(red[0], red[1]), fmaxf(red[2], red[3]));

  float ls = 0.f;
  for (int kv = tid; kv < L; kv += 256) {
    const float p = exp2a(sb[kv] - m);
    sb[kv] = p;
    ls += p;
  }
#pragma unroll
  for (int d = 1; d < 64; d <<= 1) ls += __shfl_xor(ls, d, 64);
  if (lane == 0) red[4 + w] = ls;
  __syncthreads();
  const float linv = 1.f / (red[4] + red[5] + red[6] + red[7]);

  const int d0 = (tid & 7) << 3;
  const int slot = tid >> 3;
  float acc[8];
#pragma unroll
  for (int j = 0; j < 8; j++) acc[j] = 0.f;
  for (int kv = slot; kv < L; kv += 32) {
    const float p = sb[kv];
    const s16x8 vv = *(const s16x8*)(v + ((size_t)bh * UPAD_ + kv) * 64 + d0);
#pragma unroll
    for (int j = 0; j < 8; j++) acc[j] += p * b2f(vv[j]);
  }
#pragma unroll
  for (int j = 0; j < 8; j++) obuf[slot][d0 + j] = acc[j];
  __syncthreads();
  if (tid < 64) {
    float s = 0.f;
#pragma unroll
    for (int i = 0; i < 32; i++) s += obuf[i][tid];
    x[((size_t)(b * U_ + u_q)) * 1024 + h * 64 + tid] = f2bf(s * linv);
  }
}

// ---------------- launch ----------------
extern "C" void kernel_launch(void* const* d_in, const int* in_sizes, int n_in,
                              void* d_out, int out_size, void* d_ws, size_t ws_size,
                              hipStream_t stream) {
  const float* img   = (const float*)d_in[0];
  const float* cam   = (const float*)d_in[1];
  const float* wqkv  = (const float*)d_in[2];
  const float* wproj = (const float*)d_in[3];
  const float* bias  = (const float*)d_in[4];
  const float* cosi  = (const float*)d_in[5];
  const float* sini  = (const float*)d_in[6];
  const float* cosc  = (const float*)d_in[7];
  const float* sinc  = (const float*)d_in[8];
  float* outp = (float*)d_out;

  char* ws = (char*)d_ws;
  short* Xb     = (short*)(ws + OFF_XB);
  short* Wqkvt  = (short*)(ws + OFF_WQKVT);
  short* Wprojt = (short*)(ws + OFF_WPROJT);
  short* qb     = (short*)(ws + OFF_Q);
  short* kb     = (short*)(ws + OFF_K);
  short* vb     = (short*)(ws + OFF_V);
  short* vtb    = (short*)(ws + OFF_VT);
  short* xb     = (short*)(ws + OFF_X);

  prep_kernel<<<8208, 256, 0, stream>>>(img, cam, Xb, wqkv, Wqkvt, wproj, Wprojt);
  gemm_kernel<0><<<1584, 256, 0, stream>>>(Xb, Wqkvt, cosi, sini, cosc, sinc,
                                           qb, kb, vb, nullptr, nullptr);
  vtcam_kernel<<<1312, 256, 0, stream>>>(vb, vtb, qb, kb, xb);
  attn_kernel<<<1024, 256, 0, stream>>>(qb, kb, vtb, xb);
  gemm_kernel<1><<<528, 256, 0, stream>>>(xb, Wprojt, nullptr, nullptr, nullptr, nullptr,
                                          nullptr, nullptr, nullptr, bias, outp);
}

// Round 9
// 265.998 us; speedup vs baseline: 1.4176x; 1.0190x over previous
//
#include <hip/hip_runtime.h>

// ---------------- problem constants ----------------
#define T_ 8
#define N_ 256
#define C_ 1024
#define H_ 16
#define D_ 64
#define U_ 2056      // fused tokens per batch = T*(N+1)
#define UPAD_ 2112   // 33*64
#define MROWS_ 4112  // B*U
#define MPAD_ 4224   // 33*128
#define IMG_OUT_ELEMS 4194304  // 2*8*256*1024

typedef __attribute__((ext_vector_type(4))) float f32x4;
typedef __attribute__((ext_vector_type(8))) short s16x8;
typedef __attribute__((ext_vector_type(4))) short s16x4;

__device__ __forceinline__ short f2bf(float f) {
  union { float f; unsigned u; } a; a.f = f;
  unsigned u = a.u;
  return (short)((u + 0x7fffu + ((u >> 16) & 1u)) >> 16);
}

__device__ __forceinline__ float b2f(short s) {
  union { unsigned u; float f; } a;
  a.u = ((unsigned)(unsigned short)s) << 16;
  return a.f;
}

// bare v_exp_f32 (2^x). q is pre-scaled by log2(e) so softmax runs in exp2 domain.
__device__ __forceinline__ float exp2a(float x) {
  float r; asm("v_exp_f32 %0, %1" : "=v"(r) : "v"(x)); return r;
}

__device__ __forceinline__ unsigned cvt_pk_bf16(float lo, float hi) {
  unsigned r; asm("v_cvt_pk_bf16_f32 %0, %1, %2" : "=v"(r) : "v"(lo), "v"(hi)); return r;
}

#define ASYNC_COPY16(gp, lp)                                                   \
  __builtin_amdgcn_global_load_lds((const __attribute__((address_space(1))) void*)(gp), \
                                   (__attribute__((address_space(3))) void*)(lp), 16, 0, 0)

// ---------------- workspace offsets (bytes) ----------------
constexpr size_t OFF_XB     = 0;                         // 4224*1024*2
constexpr size_t OFF_WQKVT  = OFF_XB + 8650752;          // 3072*1024*2
constexpr size_t OFF_WPROJT = OFF_WQKVT + 6291456;       // 1024*1024*2
constexpr size_t OFF_Q      = OFF_WPROJT + 2097152;      // 32*2056*64*2
constexpr size_t OFF_K      = OFF_Q + 8421376;           // 32*2112*64*2
constexpr size_t OFF_V      = OFF_K + 8650752;           // 32*2112*64*2
constexpr size_t OFF_VT     = OFF_V + 8650752;           // 32*64*2112*2
constexpr size_t OFF_X      = OFF_VT + 8650752;          // 4224*1024*2
// total ~60 MB

// ---------------- fused prep: pack X + both weight transposes ----------------
__global__ __launch_bounds__(256) void prep_kernel(const float* __restrict__ img,
                                                   const float* __restrict__ cam,
                                                   short* __restrict__ Xb,
                                                   const float* __restrict__ wqkv,
                                                   short* __restrict__ Wqkvt,
                                                   const float* __restrict__ wproj,
                                                   short* __restrict__ Wprojt) {
  __shared__ float tile[32][33];
  const int bid = blockIdx.x;
  if (bid < 4112) {
    int gt = bid * 256 + threadIdx.x;
    int e = gt << 2;                      // 4 floats per thread, exact cover of 4112*1024
    int row = e >> 10, col = e & 1023;
    int b = row / U_, u = row % U_, t = u / 257, jj = u % 257;
    const float* src = jj ? (img + ((size_t)((b * 8 + t) * 256 + (jj - 1)) << 10))
                          : (cam + ((size_t)(b * 8 + t) << 10));
    float4 f = *(const float4*)(src + col);
    s16x4 o;
    o[0] = f2bf(f.x); o[1] = f2bf(f.y); o[2] = f2bf(f.z); o[3] = f2bf(f.w);
    *(s16x4*)(Xb + ((size_t)row << 10) + col) = o;
    return;
  }
  const float* in; short* out; int Cc, bx, by;
  if (bid < 4112 + 3072) {
    int i = bid - 4112; bx = i % 96; by = i / 96; in = wqkv; out = Wqkvt; Cc = 3072;
  } else {
    int i = bid - 7184; bx = i % 32; by = i / 32; in = wproj; out = Wprojt; Cc = 1024;
  }
  constexpr int R = 1024;
  int tx = threadIdx.x & 31, ty = threadIdx.x >> 5;
  int col0 = bx << 5, row0 = by << 5;
#pragma unroll
  for (int i = 0; i < 4; i++) {
    int r = ty + i * 8;
    tile[r][tx] = in[(size_t)(row0 + r) * Cc + col0 + tx];
  }
  __syncthreads();
#pragma unroll
  for (int i = 0; i < 4; i++) {
    int r = ty + i * 8;
    out[(size_t)(col0 + r) * R + row0 + tx] = f2bf(tile[tx][r]);
  }
}

// ---------------- 64x128 bf16 GEMM, Bt is [N][K] row-major ----------------
// Double-buffered LDS; prefetch-after-barrier (T3 minimum 2-phase).
// T2 granule swizzle: physical granule = logical ^ (row&3).  Fixes the 8-way
// ds_read bank conflict of the 64B-row-stride tile (slot was (4row+quad)&7 ->
// 2 slots x 8 lanes).  global_load_lds dest stays LINEAR; the global SOURCE
// column is pre-swizzled (rule 21: both-sides involution).
// EPI 0: QKV+RoPE.  EPI 1: proj+bias.
template <int EPI>
__global__ __launch_bounds__(256) void gemm_kernel(
    const short* __restrict__ A, const short* __restrict__ Bt,
    const float* __restrict__ cosi, const float* __restrict__ sini,
    const float* __restrict__ cosc, const float* __restrict__ sinc,
    short* __restrict__ qb, short* __restrict__ kb, short* __restrict__ vb,
    const float* __restrict__ bias, float* __restrict__ outp) {
  constexpr int K = 1024;
  __shared__ __align__(16) short As[2][64 * 32];
  __shared__ __align__(16) short Bs[2][128 * 32];
  const int tid = threadIdx.x, w = tid >> 6, lane = tid & 63;
  const int l16 = lane & 15, quad = lane >> 4;

  int bn, bm;
  {
    const int flat = blockIdx.x;
    const int xcd = flat & 7, idx = flat >> 3;
    if constexpr (EPI == 0) { bn = xcd * 3 + idx / 66; bm = idx % 66; }   // 1584 blocks
    else                    { bn = xcd;                bm = idx;       }  // 528 blocks
  }

  const f32x4 zero = {0.f, 0.f, 0.f, 0.f};
  f32x4 acc[2][4];
#pragma unroll
  for (int i = 0; i < 2; i++)
#pragma unroll
    for (int j = 0; j < 4; j++) acc[i][j] = zero;

  const int mb = (w >> 1) << 5, nb = (w & 1) << 6;   // wave tile 32x64

  // staging: A 64x32 = 1 copy/thread; B 128x32 = 2 copies/thread.
  // Source column pre-swizzled by (row&3); rows r and r+64 share r&3.
  const int srow = tid >> 2;                 // 0..63
  const int cseg = (((tid & 3) ^ (srow & 3)) << 3);
  const short* gA = A + (size_t)(bm * 64 + srow) * K + cseg;
  const short* gB = Bt + (size_t)(bn * 128 + srow) * K + cseg;
  const int lo = tid * 16;                   // bytes (linear LDS dest)

#define STAGE(buf, kb0)                                                        \
  do {                                                                         \
    ASYNC_COPY16(gA + (kb0), (char*)As[buf] + lo);                             \
    ASYNC_COPY16(gB + (kb0), (char*)Bs[buf] + lo);                             \
    ASYNC_COPY16(gB + (size_t)64 * K + (kb0), (char*)Bs[buf] + lo + 4096);     \
  } while (0)

  STAGE(0, 0);
  int cur = 0;
  // read-side swizzled granule: row&3 == l16&3 for all fragment rows
  const int gsw = (quad ^ (l16 & 3)) << 3;
  for (int kb0 = 0; kb0 < K; kb0 += 32) {
    __syncthreads();                 // drains vmcnt -> buf[cur] ready
    if (kb0 + 32 < K) STAGE(cur ^ 1, kb0 + 32);   // prefetch flies under compute
    s16x8 af[2], bf[4];
#pragma unroll
    for (int mi = 0; mi < 2; mi++)
      af[mi] = *(const s16x8*)&As[cur][(mb + mi * 16 + l16) * 32 + gsw];
#pragma unroll
    for (int ni = 0; ni < 4; ni++)
      bf[ni] = *(const s16x8*)&Bs[cur][(nb + ni * 16 + l16) * 32 + gsw];
#pragma unroll
    for (int mi = 0; mi < 2; mi++)
#pragma unroll
      for (int ni = 0; ni < 4; ni++)
        acc[mi][ni] = __builtin_amdgcn_mfma_f32_16x16x32_bf16(af[mi], bf[ni], acc[mi][ni], 0, 0, 0);
    cur ^= 1;
  }
#undef STAGE

  if constexpr (EPI == 0) {
    const int cbase = bn * 128 + nb;          // wave-uniform
    const int which = cbase >> 10;            // 0=q 1=k 2=v
    const int hh = (cbase & 1023) >> 6;       // head, wave-uniform
#pragma unroll
    for (int mi = 0; mi < 2; mi++) {
#pragma unroll
      for (int reg = 0; reg < 4; reg++) {
        const int R = bm * 64 + mb + mi * 16 + quad * 4 + reg;
        if (R < MROWS_) {
          const int b = (R >= U_) ? 1 : 0;
          const int u = R - b * U_;
          const int t = (u - (u >> 8)) >> 8;  // u/257 for u<2056
          const int jj = u - ((t << 8) + t);
          const int bh = b * 16 + hh;
          if (which == 2) {
#pragma unroll
            for (int ni = 0; ni < 4; ni++)
              vb[((size_t)bh * UPAD_ + u) * 64 + ni * 16 + l16] = f2bf(acc[mi][ni][reg]);
          } else {
            const float *ct, *st; int pos;
            if (jj == 0) { ct = cosc; st = sinc; pos = t; }
            else         { ct = cosi; st = sini; pos = u - t - 1; }
#pragma unroll
            for (int ni = 0; ni < 4; ni++) {
              const int d = ni * 16 + l16;
              const float val = acc[mi][ni][reg];
              const float partner = __shfl_xor(val, 1, 64);  // d^1 neighbor, same row
              const float cv = ct[pos * 64 + d], sv = st[pos * 64 + d];
              float o = val * cv + ((d & 1) ? partner : -partner) * sv;
              if (which == 0) {
                o *= 0.18033688f;  // fold 1/sqrt(64) * log2(e) into q
                qb[((size_t)bh * U_ + u) * 64 + d] = f2bf(o);
              } else {
                kb[((size_t)bh * UPAD_ + u) * 64 + d] = f2bf(o);
              }
            }
          }
        }
      }
    }
  } else {
    const int cbase = bn * 128 + nb;
#pragma unroll
    for (int mi = 0; mi < 2; mi++) {
#pragma unroll
      for (int reg = 0; reg < 4; reg++) {
        const int R = bm * 64 + mb + mi * 16 + quad * 4 + reg;
        if (R < MROWS_) {
          const int b = (R >= U_) ? 1 : 0;
          const int u = R - b * U_;
          const int t = (u - (u >> 8)) >> 8;
          const int jj = u - ((t << 8) + t);
          size_t rowoff;
          if (jj) rowoff = (size_t)((b * 8 + t) * 256 + jj - 1) * 1024;
          else    rowoff = IMG_OUT_ELEMS + (size_t)(b * 8 + t) * 1024;
#pragma unroll
          for (int ni = 0; ni < 4; ni++) {
            const int Cg = cbase + ni * 16 + l16;
            outp[rowoff + Cg] = acc[mi][ni][reg] + bias[Cg];
          }
        }
      }
    }
  }
}

// ---------------- fused flash attention (img queries only) ----------------
// 1024 blocks, XCD decode (each XCD owns 4 bh -> K/V L2-resident).
// Swapped QK^T (T12): each lane owns ONE q-row (q=l16), softmax in-lane.
// Row-sum l runs on the MFMA pipe via a ones-column MFMA (l = P*1).
// V path: verified V^T staging (vtb from vtcam) + swizzled ds_read_b128.
__global__ __launch_bounds__(256) void attn_kernel(const short* __restrict__ q,
                                                   const short* __restrict__ k,
                                                   const short* __restrict__ vt,
                                                   short* __restrict__ x) {
  __shared__ __align__(16) short Kt[64 * 64];      // [kv][d] XOR-swizzled
  __shared__ __align__(16) short Vt[64 * 64];      // [d][kv] XOR-swizzled
  __shared__ __align__(16) short Pt[4 * 16 * 72];  // per-wave [q][kv], stride 72
  const int tid = threadIdx.x, w = tid >> 6, lane = tid & 63;
  const int l16 = lane & 15, quad = lane >> 4;
  const int flat = blockIdx.x;
  const int slot = flat >> 3;
  const int bh = ((flat & 7) << 2) + (slot >> 5);
  const int qt = slot & 31;
  const int b = bh >> 4, h = bh & 15;

  // q rows: global img row g -> fused u = g + (g>>8) + 1
  const int g = qt * 64 + w * 16 + l16;
  const int u_q = g + (g >> 8) + 1;
  const short* qp = q + ((size_t)bh * U_ + u_q) * 64;
  const s16x8 aq0 = *(const s16x8*)(qp + quad * 8);
  const s16x8 aq1 = *(const s16x8*)(qp + 32 + quad * 8);

  // reg-staging geometry: lane stages rows sr and sr+32, 16B granule c8.
  const int sr = w * 8 + (lane >> 3);              // 0..31
  const int c8 = lane & 7;
  const short* kg = k + ((size_t)bh * UPAD_ + sr) * 64 + (c8 << 3);
  const short* vg = vt + ((size_t)bh * 64 + sr) * UPAD_ + (c8 << 3);
  const int swz = ((c8 ^ (sr & 7)) << 3);          // (sr+32)&7 == sr&7
  short* const wk0 = &Kt[sr * 64 + swz];
  short* const wk1 = &Kt[(sr + 32) * 64 + swz];
  short* const wv0 = &Vt[sr * 64 + swz];
  short* const wv1 = &Vt[(sr + 32) * 64 + swz];

  // swizzled LDS read columns (shorts); row = ni*16+l16 -> row&7 = l16&7
  const int cK0 = (quad * 8) ^ ((l16 & 7) << 3);
  const int cK1 = (32 + quad * 8) ^ ((l16 & 7) << 3);
  short* const pw = Pt + (w * 16 + l16) * 72;

  const f32x4 zero = {0.f, 0.f, 0.f, 0.f};
  const s16x8 vones = {16256, 16256, 16256, 16256, 16256, 16256, 16256, 16256}; // bf16 1.0
  float m_r = -3e38f;
  f32x4 l_acc = zero;
  f32x4 o_acc[4];
#pragma unroll
  for (int r = 0; r < 4; r++) o_acc[r] = zero;

  // prologue: stage tile 0 into regs
  s16x8 rk0 = *(const s16x8*)(kg);
  s16x8 rk1 = *(const s16x8*)(kg + 2048);
  s16x8 rv0 = *(const s16x8*)(vg);
  s16x8 rv1 = *(const s16x8*)(vg + 32 * UPAD_);
  kg += 64 * 64;
  vg += 64;

  for (int kv0 = 0; kv0 < U_; kv0 += 64) {
    __syncthreads();                 // prev tile's LDS reads complete
    *(s16x8*)wk0 = rk0;
    *(s16x8*)wk1 = rk1;
    *(s16x8*)wv0 = rv0;
    *(s16x8*)wv1 = rv1;
    __syncthreads();                 // LDS ready
    if (kv0 + 64 < U_) {             // issue next-tile loads; hide under compute
      rk0 = *(const s16x8*)(kg);
      rk1 = *(const s16x8*)(kg + 2048);
      rv0 = *(const s16x8*)(vg);
      rv1 = *(const s16x8*)(vg + 32 * UPAD_);
      kg += 64 * 64;
      vg += 64;
    }

    // S^T = K Q^T: C row = kv (ni*16+quad*4+reg), col = q = l16
    f32x4 sT[4];
    __builtin_amdgcn_s_setprio(1);
#pragma unroll
    for (int ni = 0; ni < 4; ni++) {
      const s16x8 b0 = *(const s16x8*)&Kt[(ni * 16 + l16) * 64 + cK0];
      const s16x8 b1 = *(const s16x8*)&Kt[(ni * 16 + l16) * 64 + cK1];
      f32x4 z = __builtin_amdgcn_mfma_f32_16x16x32_bf16(b0, aq0, zero, 0, 0, 0);
      sT[ni] = __builtin_amdgcn_mfma_f32_16x16x32_bf16(b1, aq1, z, 0, 0, 0);
    }
    __builtin_amdgcn_s_setprio(0);

    // tail tile: real kv are 2048..2055 -> kv_local = ni*16+quad*4+reg < 8
    if (kv0 == 2048) {
#pragma unroll
      for (int ni = 0; ni < 4; ni++) {
        if (ni > 0 || quad >= 2) {
          sT[ni][0] = -1e30f; sT[ni][1] = -1e30f;
          sT[ni][2] = -1e30f; sT[ni][3] = -1e30f;
        }
      }
    }

    // in-lane row max (v_max3 tree) + 2 cross-lane ops
    float t0 = fmaxf(fmaxf(sT[0][0], sT[0][1]), sT[0][2]);
    float t1 = fmaxf(fmaxf(sT[0][3], sT[1][0]), sT[1][1]);
    float t2 = fmaxf(fmaxf(sT[1][2], sT[1][3]), sT[2][0]);
    float t3 = fmaxf(fmaxf(sT[2][1], sT[2][2]), sT[2][3]);
    float t4 = fmaxf(fmaxf(sT[3][0], sT[3][1]), sT[3][2]);
    float mx = fmaxf(fmaxf(fmaxf(t0, t1), t2), fmaxf(fmaxf(t3, t4), sT[3][3]));
    mx = fmaxf(mx, __shfl_xor(mx, 16, 64));
    mx = fmaxf(mx, __shfl_xor(mx, 32, 64));

    // T13 defer-max: rescale only when max grew by >= 8 (exp2 domain)
    if (__any(mx > m_r + 8.f)) {
      const float mnew = fmaxf(m_r, mx);
      const float al = exp2a(m_r - mnew);
      m_r = mnew;
      float aR[4];
#pragma unroll
      for (int reg = 0; reg < 4; reg++) aR[reg] = __shfl(al, quad * 4 + reg, 64);
#pragma unroll
      for (int ni = 0; ni < 4; ni++)
#pragma unroll
        for (int reg = 0; reg < 4; reg++) o_acc[ni][reg] *= aR[reg];
#pragma unroll
      for (int reg = 0; reg < 4; reg++) l_acc[reg] *= aR[reg];
    }

#pragma unroll
    for (int ni = 0; ni < 4; ni++)
#pragma unroll
      for (int reg = 0; reg < 4; reg++)
        sT[ni][reg] = exp2a(sT[ni][reg] - m_r);

    // P -> Pt[q=l16][kv]: one b64 per ni
#pragma unroll
    for (int ni = 0; ni < 4; ni++) {
      uint2 pk;
      pk.x = cvt_pk_bf16(sT[ni][0], sT[ni][1]);
      pk.y = cvt_pk_bf16(sT[ni][2], sT[ni][3]);
      *(uint2*)&pw[ni * 16 + quad * 4] = pk;
    }

    // O += P V ;  l += P * 1  (row-sum on the MFMA pipe)
    const s16x8 ap0 = *(const s16x8*)&pw[quad * 8];
    const s16x8 ap1 = *(const s16x8*)&pw[32 + quad * 8];
    __builtin_amdgcn_s_setprio(1);
    l_acc = __builtin_amdgcn_mfma_f32_16x16x32_bf16(ap0, vones, l_acc, 0, 0, 0);
#pragma unroll
    for (int ni = 0; ni < 4; ni++) {
      const s16x8 bv = *(const s16x8*)&Vt[(ni * 16 + l16) * 64 + cK0];
      o_acc[ni] = __builtin_amdgcn_mfma_f32_16x16x32_bf16(ap0, bv, o_acc[ni], 0, 0, 0);
    }
    l_acc = __builtin_amdgcn_mfma_f32_16x16x32_bf16(ap1, vones, l_acc, 0, 0, 0);
#pragma unroll
    for (int ni = 0; ni < 4; ni++) {
      const s16x8 bv = *(const s16x8*)&Vt[(ni * 16 + l16) * 64 + cK1];
      o_acc[ni] = __builtin_amdgcn_mfma_f32_16x16x32_bf16(ap1, bv, o_acc[ni], 0, 0, 0);
    }
    __builtin_amdgcn_s_setprio(0);
  }

  // l_acc already in o_acc layout (row = quad*4+reg); all 16 cols identical
  f32x4 linv;
#pragma unroll
  for (int reg = 0; reg < 4; reg++) linv[reg] = 1.f / l_acc[reg];

  // write x[b*2056+u][h*64+d] bf16 (o row = quad*4+reg, col = ni*16+l16)
#pragma unroll
  for (int reg = 0; reg < 4; reg++) {
    const int go = qt * 64 + w * 16 + quad * 4 + reg;
    const int u_o = go + (go >> 8) + 1;
#pragma unroll
    for (int ni = 0; ni < 4; ni++)
      x[((size_t)(b * U_ + u_o)) * 1024 + h * 64 + ni * 16 + l16] =
          f2bf(o_acc[ni][reg] * linv[reg]);
  }
}

// ---------------- fused vt transpose + cam-query attention ----------------
// blocks 0..1055: bf16 v[bh][2112][64] -> vt[bh][64][2112] (zero pad rows)
// blocks 1056..1311: cam attention; decode puts all 8 t-blocks of a bh on the
// SAME XCD (block_id%8 == bh&7) so K/V re-reads hit that XCD's L2.
__global__ __launch_bounds__(256) void vtcam_kernel(const short* __restrict__ v,
                                                    short* __restrict__ vt,
                                                    const short* __restrict__ q,
                                                    const short* __restrict__ k,
                                                    short* __restrict__ x) {
  __shared__ __align__(16) char smem[16448];
  const int bid = blockIdx.x;
  const int tid = threadIdx.x;
  if (bid < 1056) {
    short (*t2)[65] = (short(*)[65])smem;          // 64*65*2 = 8320 B
    int kt = bid % 33, bh = bid / 33;
#pragma unroll
    for (int i = 0; i < 16; i++) {
      int e = tid + i * 256; int r = e >> 6, c = e & 63;
      short vv = v[((size_t)bh * UPAD_ + kt * 64 + r) * 64 + c];
      t2[r][c] = (kt * 64 + r < U_) ? vv : (short)0;
    }
    __syncthreads();
#pragma unroll
    for (int i = 0; i < 16; i++) {
      int e = tid + i * 256; int d = e >> 6, c = e & 63;
      vt[((size_t)bh * 64 + d) * UPAD_ + kt * 64 + c] = t2[c][d];
    }
    return;
  }
  float* sb = (float*)smem;                        // 2056 floats
  float* red = sb + U_;                            // 8 floats
  float (*obuf)[64] = (float(*)[64])(red + 8);     // 32*64 floats
  const int i0 = bid - 1056;                       // XCD of this block = i0 & 7
  const int bh = (i0 & 7) + ((i0 >> 6) << 3);      // bh&7 == i0&7 -> same XCD per bh
  const int t = (i0 >> 3) & 7;
  const int b = bh >> 4, h = bh & 15;
  const int L = (t + 1) * 257;
  const int lane = tid & 63, w = tid >> 6;
  const int u_q = t * 257;

  float qf[64];
  {
    const short* qpp = q + ((size_t)bh * U_ + u_q) * 64;
#pragma unroll
    for (int i = 0; i < 8; i++) {
      const s16x8 qv = *(const s16x8*)(qpp + i * 8);
#pragma unroll
      for (int j = 0; j < 8; j++) qf[i * 8 + j] = b2f(qv[j]);
    }
  }

  float lm = -3e38f;
  for (int kv = tid; kv < L; kv += 256) {
    const short* kp = k + ((size_t)bh * UPAD_ + kv) * 64;
    float s = 0.f;
#pragma unroll
    for (int i = 0; i < 8; i++) {
      const s16x8 kvv = *(const s16x8*)(kp + i * 8);
#pragma unroll
      for (int j = 0; j < 8; j++) s += qf[i * 8 + j] * b2f(kvv[j]);
    }
    sb[kv] = s;
    lm = fmaxf(lm, s);
  }
#pragma unroll
  for (int d = 1; d < 64; d <<= 1) lm = fmaxf(lm, __shfl_xor(lm, d, 64));
  if (lane == 0) red[w] = lm;
  __syncthreads();
  const float m = fmaxf(fmaxf(red[0], red[1]), fmaxf(red[2], red[3]));

  float ls = 0.f;
  for (int kv = tid; kv < L; kv += 256) {
    const float p = exp2a(sb[kv] - m);
    sb[kv] = p;
    ls += p;
  }
#pragma unroll
  for (int d = 1; d < 64; d <<= 1) ls += __shfl_xor(ls, d, 64);
  if (lane == 0) red[4 + w] = ls;
  __syncthreads();
  const float linv = 1.f / (red[4] + red[5] + red[6] + red[7]);

  const int d0 = (tid & 7) << 3;
  const int slot = tid >> 3;
  float acc[8];
#pragma unroll
  for (int j = 0; j < 8; j++) acc[j] = 0.f;
  for (int kv = slot; kv < L; kv += 32) {
    const float p = sb[kv];
    const s16x8 vv = *(const s16x8*)(v + ((size_t)bh * UPAD_ + kv) * 64 + d0);
#pragma unroll
    for (int j = 0; j < 8; j++) acc[j] += p * b2f(vv[j]);
  }
#pragma unroll
  for (int j = 0; j < 8; j++) obuf[slot][d0 + j] = acc[j];
  __syncthreads();
  if (tid < 64) {
    float s = 0.f;
#pragma unroll
    for (int i = 0; i < 32; i++) s += obuf[i][tid];
    x[((size_t)(b * U_ + u_q)) * 1024 + h * 64 + tid] = f2bf(s * linv);
  }
}

// ---------------- launch ----------------
extern "C" void kernel_launch(void* const* d_in, const int* in_sizes, int n_in,
                              void* d_out, int out_size, void* d_ws, size_t ws_size,
                              hipStream_t stream) {
  const float* img   = (const float*)d_in[0];
  const float* cam   = (const float*)d_in[1];
  const float* wqkv  = (const float*)d_in[2];
  const float* wproj = (const float*)d_in[3];
  const float* bias  = (const float*)d_in[4];
  const float* cosi  = (const float*)d_in[5];
  const float* sini  = (const float*)d_in[6];
  const float* cosc  = (const float*)d_in[7];
  const float* sinc  = (const float*)d_in[8];
  float* outp = (float*)d_out;

  char* ws = (char*)d_ws;
  short* Xb     = (short*)(ws + OFF_XB);
  short* Wqkvt  = (short*)(ws + OFF_WQKVT);
  short* Wprojt = (short*)(ws + OFF_WPROJT);
  short* qb     = (short*)(ws + OFF_Q);
  short* kb     = (short*)(ws + OFF_K);
  short* vb     = (short*)(ws + OFF_V);
  short* vtb    = (short*)(ws + OFF_VT);
  short* xb     = (short*)(ws + OFF_X);

  prep_kernel<<<8208, 256, 0, stream>>>(img, cam, Xb, wqkv, Wqkvt, wproj, Wprojt);
  gemm_kernel<0><<<1584, 256, 0, stream>>>(Xb, Wqkvt, cosi, sini, cosc, sinc,
                                           qb, kb, vb, nullptr, nullptr);
  vtcam_kernel<<<1312, 256, 0, stream>>>(vb, vtb, qb, kb, xb);
  attn_kernel<<<1024, 256, 0, stream>>>(qb, kb, vtb, xb);
  gemm_kernel<1><<<528, 256, 0, stream>>>(xb, Wprojt, nullptr, nullptr, nullptr, nullptr,
                                          nullptr, nullptr, nullptr, bias, outp);
}